// Round 12
// baseline (250.282 us; speedup 1.0000x reference)
//
#include <hip/hip_runtime.h>
#include <hip/hip_fp16.h>

typedef _Float16 f16;
typedef _Float16 f16x8 __attribute__((ext_vector_type(8)));
typedef __fp16 h16x2 __attribute__((ext_vector_type(2)));
typedef float f32x4 __attribute__((ext_vector_type(4)));
typedef float f32x16 __attribute__((ext_vector_type(16)));

#define LOG2E 1.4426950408889634f
#define NSL 0.2f

// ---------------- Kernel 1: graph -> j-major transposed bitmask (+ init M2e) ----------------
__global__ __launch_bounds__(256) void k_mask(const int* __restrict__ graph,
                                              unsigned int* __restrict__ maskJ,
                                              unsigned int* __restrict__ M2e) {
    if (blockIdx.x == 0 && threadIdx.x < 8) M2e[threadIdx.x] = 0x007FFFFFu;  // enc(-inf)
    __shared__ unsigned long long bal[4][64];
    int w = threadIdx.x >> 6;
    int lane = threadIdx.x & 63;
    int gw = blockIdx.x * 4 + w;
    int ti = gw & 63, tj = gw >> 6;
    int i0 = ti * 64, j0 = tj * 64;
    #pragma unroll 8
    for (int k = 0; k < 64; k++) {
        int g = graph[(j0 + k) * 4096 + i0 + lane];
        unsigned long long b = __ballot(g > 0);
        if (lane == 0) bal[w][k] = b;
    }
    __syncthreads();
    unsigned long long word = 0;
    #pragma unroll 8
    for (int k = 0; k < 64; k++) {
        word |= ((bal[w][k] >> lane) & 1ull) << k;
    }
    int jw = j0 >> 5;
    maskJ[(size_t)jw * 4096 + i0 + lane]       = (unsigned int)word;
    maskJ[(size_t)(jw + 1) * 4096 + i0 + lane] = (unsigned int)(word >> 32);
}

// ---------------- Kernel 2 (fused prep): xcvt + swizzled weight transposes ----------------
__device__ void dev_transpose_sw(const float* __restrict__ in, f16* __restrict__ out,
                                 int C, int S, int bxx, int byy, int tid) {
    __shared__ float tile[32][33];
    int tx = tid & 31, ty = tid >> 5;
    int c0 = bxx * 32, r0 = byy * 32;
    for (int rr = ty; rr < 32; rr += 8)
        tile[rr][tx] = in[(r0 + rr) * C + c0 + tx];
    __syncthreads();
    for (int rr = ty; rr < 32; rr += 8) {
        int m = r0 + tx, f = c0 + rr;
        out[(size_t)((m >> 4) * S + f) * 16 + (m & 15)] = (f16)tile[tx][rr];
    }
}

__global__ __launch_bounds__(256) void k_pre(const float* __restrict__ x,
                                             f16* __restrict__ xh2,
                                             const float* __restrict__ W,
                                             f16* __restrict__ Wht2,
                                             const float* __restrict__ Wr,
                                             f16* __restrict__ Wrt2) {
    int bx = blockIdx.x;
    int tid = threadIdx.x;
    if (bx < 512) {
        int id = bx * 256 + tid;   // 131072
        int row = id & 4095, kt = id >> 12;
        const float4* xs = (const float4*)(x + (size_t)row * 512 + kt * 16);
        float4 u0 = xs[0], u1 = xs[1], u2 = xs[2], u3 = xs[3];
        union { int4 a[2]; h16x2 p[8]; } px;
        px.p[0] = __builtin_amdgcn_cvt_pkrtz(u0.x, u0.y);
        px.p[1] = __builtin_amdgcn_cvt_pkrtz(u0.z, u0.w);
        px.p[2] = __builtin_amdgcn_cvt_pkrtz(u1.x, u1.y);
        px.p[3] = __builtin_amdgcn_cvt_pkrtz(u1.z, u1.w);
        px.p[4] = __builtin_amdgcn_cvt_pkrtz(u2.x, u2.y);
        px.p[5] = __builtin_amdgcn_cvt_pkrtz(u2.z, u2.w);
        px.p[6] = __builtin_amdgcn_cvt_pkrtz(u3.x, u3.y);
        px.p[7] = __builtin_amdgcn_cvt_pkrtz(u3.z, u3.w);
        int4* d = (int4*)(xh2 + ((size_t)kt * 4096 + row) * 16);
        d[0] = px.a[0]; d[1] = px.a[1];
    } else if (bx < 1024) {
        int id = bx - 512;                       // W -> Wht2
        dev_transpose_sw(W, Wht2, 128, 128, id & 3, id >> 2, tid);
    } else {
        int id = bx - 1024;                      // Wr -> Wrt2
        dev_transpose_sw(Wr, Wrt2, 1024, 1024, id & 31, id >> 5, tid);
    }
}

// ---------------- Kernel 3: hbT2 + fused a2/b2 + per-head max ----------------
__global__ __launch_bounds__(256, 4) void k_gemm_h(const f16* __restrict__ xh2,
                                                   const f16* __restrict__ Wht2,
                                                   f16* __restrict__ hbT2,
                                                   const float* __restrict__ wi,
                                                   const float* __restrict__ wj,
                                                   float* __restrict__ a2,
                                                   float* __restrict__ b2,
                                                   unsigned int* __restrict__ M2e) {
    __shared__ float swi[128], swj[128];
    __shared__ float pwa[4][32], pwb[4][32];
    int bx = blockIdx.x;
    int h = bx & 7, jb = bx >> 3;        // 128 j-tiles of 32
    int j0 = jb * 32;
    int tid = threadIdx.x;
    int w = tid >> 6, lane = tid & 63;
    int ln = lane & 15, q = lane >> 4;
    if (tid < 128) { swi[tid] = wi[h * 128 + tid]; swj[tid] = wj[h * 128 + tid]; }
    __syncthreads();

    int ko = (q & 1) * 8;
    const f16* pa = Wht2 + ((size_t)(h * 512) * 8 + (size_t)(q >> 1) * 128 + w * 32 + ln) * 16 + ko;
    const f16* pb = xh2 + ((size_t)(q >> 1) * 4096 + j0 + ln) * 16 + ko;

    f32x4 acc00 = {}, acc01 = {}, acc10 = {}, acc11 = {};

    f16x8 ra0 = *(const f16x8*)(pa);
    f16x8 ra1 = *(const f16x8*)(pa + 256);
    f16x8 rb0 = *(const f16x8*)(pb);
    f16x8 rb1 = *(const f16x8*)(pb + 256);

    for (int kk = 0; kk < 8; kk++) {
        f16x8 sa0 = *(const f16x8*)(pa + 4096);
        f16x8 sa1 = *(const f16x8*)(pa + 4096 + 256);
        f16x8 sb0 = *(const f16x8*)(pb + 131072);
        f16x8 sb1 = *(const f16x8*)(pb + 131072 + 256);
        acc00 = __builtin_amdgcn_mfma_f32_16x16x32_f16(ra0, rb0, acc00, 0, 0, 0);
        acc01 = __builtin_amdgcn_mfma_f32_16x16x32_f16(ra0, rb1, acc01, 0, 0, 0);
        acc10 = __builtin_amdgcn_mfma_f32_16x16x32_f16(ra1, rb0, acc10, 0, 0, 0);
        acc11 = __builtin_amdgcn_mfma_f32_16x16x32_f16(ra1, rb1, acc11, 0, 0, 0);
        pa += 8192; pb += 262144;
        ra0 = *(const f16x8*)(pa);
        ra1 = *(const f16x8*)(pa + 256);
        rb0 = *(const f16x8*)(pb);
        rb1 = *(const f16x8*)(pb + 256);
        acc00 = __builtin_amdgcn_mfma_f32_16x16x32_f16(sa0, sb0, acc00, 0, 0, 0);
        acc01 = __builtin_amdgcn_mfma_f32_16x16x32_f16(sa0, sb1, acc01, 0, 0, 0);
        acc10 = __builtin_amdgcn_mfma_f32_16x16x32_f16(sa1, sb0, acc10, 0, 0, 0);
        acc11 = __builtin_amdgcn_mfma_f32_16x16x32_f16(sa1, sb1, acc11, 0, 0, 0);
    }

    size_t hb = (size_t)h * 524288 + (size_t)(j0 >> 4) * 2048;
    #pragma unroll
    for (int r = 0; r < 4; r++) {
        int f0 = w * 32 + q * 4 + r;
        hbT2[hb + f0 * 16 + ln]                 = (f16)acc00[r];
        hbT2[hb + 2048 + f0 * 16 + ln]          = (f16)acc01[r];
        hbT2[hb + (f0 + 16) * 16 + ln]          = (f16)acc10[r];
        hbT2[hb + 2048 + (f0 + 16) * 16 + ln]   = (f16)acc11[r];
    }

    float pa0 = 0.f, pb0 = 0.f, pa1 = 0.f, pb1 = 0.f;
    #pragma unroll
    for (int r = 0; r < 4; r++) {
        int f0 = w * 32 + q * 4 + r;
        float w0 = swi[f0], jv0 = swj[f0];
        float w1 = swi[f0 + 16], jv1 = swj[f0 + 16];
        pa0 += acc00[r] * w0 + acc10[r] * w1;
        pb0 += acc00[r] * jv0 + acc10[r] * jv1;
        pa1 += acc01[r] * w0 + acc11[r] * w1;
        pb1 += acc01[r] * jv0 + acc11[r] * jv1;
    }
    pa0 += __shfl_xor(pa0, 16); pa0 += __shfl_xor(pa0, 32);
    pb0 += __shfl_xor(pb0, 16); pb0 += __shfl_xor(pb0, 32);
    pa1 += __shfl_xor(pa1, 16); pa1 += __shfl_xor(pa1, 32);
    pb1 += __shfl_xor(pb1, 16); pb1 += __shfl_xor(pb1, 32);
    if (lane < 16) {
        pwa[w][ln] = pa0;      pwb[w][ln] = pb0;
        pwa[w][16 + ln] = pa1; pwb[w][16 + ln] = pb1;
    }
    __syncthreads();
    if (tid < 32) {
        int jj = tid;
        float pav = (pwa[0][jj] + pwa[1][jj]) + (pwa[2][jj] + pwa[3][jj]);
        float pbv = (pwb[0][jj] + pwb[1][jj]) + (pwb[2][jj] + pwb[3][jj]);
        a2[h * 4096 + j0 + jj] = pav * LOG2E;
        float bb = pbv * LOG2E;
        b2[h * 4096 + j0 + jj] = bb;
        float m = bb;
        m = fmaxf(m, __shfl_xor(m, 1, 32));
        m = fmaxf(m, __shfl_xor(m, 2, 32));
        m = fmaxf(m, __shfl_xor(m, 4, 32));
        m = fmaxf(m, __shfl_xor(m, 8, 32));
        m = fmaxf(m, __shfl_xor(m, 16, 32));
        if (jj == 0) {
            unsigned u = __float_as_uint(m);
            unsigned enc = (u & 0x80000000u) ? ~u : (u | 0x80000000u);
            atomicMax(&M2e[h], enc);
        }
    }
}

// ---------------- Kernel 5: exp tables ----------------
__global__ __launch_bounds__(256) void k_prep(const float* __restrict__ a2,
                                              const float* __restrict__ b2,
                                              const unsigned int* __restrict__ M2e,
                                              float* __restrict__ ABpre,
                                              float* __restrict__ Bpre) {
    int id = blockIdx.x * 256 + threadIdx.x;   // 32768
    int h = id >> 12;
    unsigned enc = M2e[h];
    unsigned u = (enc & 0x80000000u) ? (enc & 0x7FFFFFFFu) : ~enc;
    float M2 = __uint_as_float(u);
    float av = a2[id];
    float t = av + M2;
    float m2 = fmaxf(t, NSL * t);
    ((float2*)ABpre)[id] = make_float2(exp2f(av - m2), exp2f(NSL * av - m2));
    float bv = b2[id];
    ((float2*)Bpre)[id] = make_float2(exp2f(bv), exp2f(NSL * bv));
}

// ---------------- Kernel 6 helpers ----------------
// parameterized P-generation: q0..q3 preloaded float4s shared by both i-halves
#define PGEN(af, m8, Aiv, Ai2v, dsumv)                                               \
    {                                                                                \
        float e0, e1;                                                                \
        e0 = fmaxf(Aiv * q0.x, Ai2v * q0.y); e1 = fmaxf(Aiv * q0.z, Ai2v * q0.w);    \
        e0 = ((m8) & 1u) ? e0 : 0.f;  e1 = ((m8) & 2u) ? e1 : 0.f;                   \
        dsumv += e0 + e1; af.p[0] = __builtin_amdgcn_cvt_pkrtz(e0, e1);              \
        e0 = fmaxf(Aiv * q1.x, Ai2v * q1.y); e1 = fmaxf(Aiv * q1.z, Ai2v * q1.w);    \
        e0 = ((m8) & 4u) ? e0 : 0.f;  e1 = ((m8) & 8u) ? e1 : 0.f;                   \
        dsumv += e0 + e1; af.p[1] = __builtin_amdgcn_cvt_pkrtz(e0, e1);              \
        e0 = fmaxf(Aiv * q2.x, Ai2v * q2.y); e1 = fmaxf(Aiv * q2.z, Ai2v * q2.w);    \
        e0 = ((m8) & 16u) ? e0 : 0.f; e1 = ((m8) & 32u) ? e1 : 0.f;                  \
        dsumv += e0 + e1; af.p[2] = __builtin_amdgcn_cvt_pkrtz(e0, e1);              \
        e0 = fmaxf(Aiv * q3.x, Ai2v * q3.y); e1 = fmaxf(Aiv * q3.z, Ai2v * q3.w);    \
        e0 = ((m8) & 64u) ? e0 : 0.f; e1 = ((m8) & 128u) ? e1 : 0.f;                 \
        dsumv += e0 + e1; af.p[3] = __builtin_amdgcn_cvt_pkrtz(e0, e1);              \
    }

#define PUTACC(dp, off, accv)                                                    \
    {                                                                            \
        union { f32x16 v; f32x4 q[4]; } t; t.v = (accv);                         \
        *(f32x4*)((dp) + (off))      = t.q[0];                                   \
        *(f32x4*)((dp) + (off) + 4)  = t.q[1];                                   \
        *(f32x4*)((dp) + (off) + 8)  = t.q[2];                                   \
        *(f32x4*)((dp) + (off) + 12) = t.q[3];                                   \
    }

#define ADDACC(dp, off, accv)                                                    \
    {                                                                            \
        union { f32x16 v; f32x4 q[4]; } t; t.v = (accv);                         \
        t.q[0] += *(const f32x4*)((dp) + (off));                                 \
        t.q[1] += *(const f32x4*)((dp) + (off) + 4);                             \
        t.q[2] += *(const f32x4*)((dp) + (off) + 8);                             \
        t.q[3] += *(const f32x4*)((dp) + (off) + 12);                            \
        (accv) = t.v;                                                            \
    }

// ---------------- Kernel 6: main — 64-i waves (each B-frag feeds 8 MFMAs) ----------------
// Block = (h=bx&7 XCD-pinned, 64-i strip). Wave w = j-quarter. 2 A-frags (i, i+32) per wave
// halve per-CU B-fragment L2 traffic. 8 accs = 128 AGPR; launch_bounds(256,2) = 256-reg cap.
__global__ __launch_bounds__(256, 2) void k_main(const f16* __restrict__ xh2,
                                                 const f16* __restrict__ hbT2,
                                                 const f16* __restrict__ Wrt2,
                                                 const unsigned int* __restrict__ maskJ,
                                                 const float* __restrict__ ABpre,
                                                 const float* __restrict__ Bpre,
                                                 const float* __restrict__ bias,
                                                 float* __restrict__ out) {
    __shared__ float xred[2][64 * 68];   // 34816 B (reused for both i-half passes)
    __shared__ float dred[256];

    int bx = blockIdx.x;
    int h = bx & 7, it = bx >> 3;        // 64 strips of 64 i
    int i0 = it * 64;
    int tid = threadIdx.x;
    int w = tid >> 6, lane = tid & 63;
    int l31 = lane & 31, half = lane >> 5;
    int ia = i0 + l31;                   // first i-half row
    int ib = ia + 32;                    // second i-half row

    float2 Ava = *(const float2*)(ABpre + 2 * (h * 4096 + ia));
    float2 Avb = *(const float2*)(ABpre + 2 * (h * 4096 + ib));
    float Aia = Ava.x, Ai2a = Ava.y;
    float Aib = Avb.x, Ai2b = Avb.y;

    f32x16 acc0 = {}, acc1 = {}, acc2 = {}, acc3 = {};   // i-half a
    f32x16 acc4 = {}, acc5 = {}, acc6 = {}, acc7 = {};   // i-half b
    float dsa = 0.f, dsb = 0.f;

    int J0 = w * 1024;
    const f16* bb = hbT2 + (size_t)h * 524288 + ((size_t)(J0 >> 4) * 128 + l31) * 16 + half * 8;
    const float* bp0 = Bpre + 2 * (h * 4096 + J0) + half * 16;
    const unsigned int* mra = maskJ + (size_t)(J0 >> 5) * 4096 + ia;
    const unsigned int* mrb = mra + 32;

    int sh0 = half << 3;
    int sh1 = 16 + (half << 3);

    // statically-named double buffers (4 frags = 128 f)
    f16x8 fa0 = *(const f16x8*)(bb);
    f16x8 fa1 = *(const f16x8*)(bb + 512);
    f16x8 fa2 = *(const f16x8*)(bb + 1024);
    f16x8 fa3 = *(const f16x8*)(bb + 1536);

    for (int tt = 0; tt < 32; tt++) {
        int t0 = tt * 2;
        unsigned mwa = mra[(size_t)tt * 4096];
        unsigned mwb = mrb[(size_t)tt * 4096];

        // prefetch t0+1 into b-buffers
        const f16* s1 = bb + (size_t)(t0 + 1) * 2048;
        f16x8 fb0 = *(const f16x8*)(s1);
        f16x8 fb1 = *(const f16x8*)(s1 + 512);
        f16x8 fb2 = *(const f16x8*)(s1 + 1024);
        f16x8 fb3 = *(const f16x8*)(s1 + 1536);

        // body even t0 (a-buffers)
        {
            const float4* bpq = (const float4*)(bp0 + t0 * 32);
            float4 q0 = bpq[0], q1 = bpq[1], q2 = bpq[2], q3 = bpq[3];
            union { f16x8 v; h16x2 p[4]; } afa;
            PGEN(afa, mwa >> sh0, Aia, Ai2a, dsa);
            acc0 = __builtin_amdgcn_mfma_f32_32x32x16_f16(afa.v, fa0, acc0, 0, 0, 0);
            acc1 = __builtin_amdgcn_mfma_f32_32x32x16_f16(afa.v, fa1, acc1, 0, 0, 0);
            acc2 = __builtin_amdgcn_mfma_f32_32x32x16_f16(afa.v, fa2, acc2, 0, 0, 0);
            acc3 = __builtin_amdgcn_mfma_f32_32x32x16_f16(afa.v, fa3, acc3, 0, 0, 0);
            union { f16x8 v; h16x2 p[4]; } afb;
            PGEN(afb, mwb >> sh0, Aib, Ai2b, dsb);
            acc4 = __builtin_amdgcn_mfma_f32_32x32x16_f16(afb.v, fa0, acc4, 0, 0, 0);
            acc5 = __builtin_amdgcn_mfma_f32_32x32x16_f16(afb.v, fa1, acc5, 0, 0, 0);
            acc6 = __builtin_amdgcn_mfma_f32_32x32x16_f16(afb.v, fa2, acc6, 0, 0, 0);
            acc7 = __builtin_amdgcn_mfma_f32_32x32x16_f16(afb.v, fa3, acc7, 0, 0, 0);
        }

        // prefetch t0+2 into a-buffers (last-iter overrun stays inside workspace)
        const f16* s2 = bb + (size_t)(t0 + 2) * 2048;
        fa0 = *(const f16x8*)(s2);
        fa1 = *(const f16x8*)(s2 + 512);
        fa2 = *(const f16x8*)(s2 + 1024);
        fa3 = *(const f16x8*)(s2 + 1536);

        // body odd t0+1 (b-buffers)
        {
            const float4* bpq = (const float4*)(bp0 + (t0 + 1) * 32);
            float4 q0 = bpq[0], q1 = bpq[1], q2 = bpq[2], q3 = bpq[3];
            union { f16x8 v; h16x2 p[4]; } afa;
            PGEN(afa, mwa >> sh1, Aia, Ai2a, dsa);
            acc0 = __builtin_amdgcn_mfma_f32_32x32x16_f16(afa.v, fb0, acc0, 0, 0, 0);
            acc1 = __builtin_amdgcn_mfma_f32_32x32x16_f16(afa.v, fb1, acc1, 0, 0, 0);
            acc2 = __builtin_amdgcn_mfma_f32_32x32x16_f16(afa.v, fb2, acc2, 0, 0, 0);
            acc3 = __builtin_amdgcn_mfma_f32_32x32x16_f16(afa.v, fb3, acc3, 0, 0, 0);
            union { f16x8 v; h16x2 p[4]; } afb;
            PGEN(afb, mwb >> sh1, Aib, Ai2b, dsb);
            acc4 = __builtin_amdgcn_mfma_f32_32x32x16_f16(afb.v, fb0, acc4, 0, 0, 0);
            acc5 = __builtin_amdgcn_mfma_f32_32x32x16_f16(afb.v, fb1, acc5, 0, 0, 0);
            acc6 = __builtin_amdgcn_mfma_f32_32x32x16_f16(afb.v, fb2, acc6, 0, 0, 0);
            acc7 = __builtin_amdgcn_mfma_f32_32x32x16_f16(afb.v, fb3, acc7, 0, 0, 0);
        }
    }

    // ---- denominators: in-wave j-half combine, cross-wave via LDS ----
    dsa += __shfl(dsa, lane ^ 32);
    dsb += __shfl(dsb, lane ^ 32);
    if (lane < 32) { dred[w * 32 + l31] = dsa; dred[128 + w * 32 + l31] = dsb; }
    __syncthreads();
    {
        #pragma unroll
        for (int r = 0; r < 16; r++) {
            int row = (r & 3) + 8 * (r >> 2) + 4 * half;
            float sa = dred[row] + dred[32 + row] + dred[64 + row] + dred[96 + row];
            float sb = dred[128 + row] + dred[160 + row] + dred[192 + row] + dred[224 + row];
            float iva = 1.0f / sa, ivb = 1.0f / sb;
            acc0[r] *= iva; acc1[r] *= iva; acc2[r] *= iva; acc3[r] *= iva;
            acc4[r] *= ivb; acc5[r] *= ivb; acc6[r] *= ivb; acc7[r] *= ivb;
        }
    }

    // ---- residual: both i-halves; k-quarter per wave, shared W-frag loads ----
    {
        #pragma unroll
        for (int kt = 0; kt < 8; kt++) {
            int ktt = w * 8 + kt;
            f16x8 axa = *(const f16x8*)(xh2 + ((size_t)ktt * 4096 + ia) * 16 + half * 8);
            f16x8 axb = *(const f16x8*)(xh2 + ((size_t)ktt * 4096 + ib) * 16 + half * 8);
            const f16* wb = Wrt2 + ((size_t)ktt * 1024 + h * 128 + l31) * 16 + half * 8;
            f16x8 w0 = *(const f16x8*)(wb);
            f16x8 w1 = *(const f16x8*)(wb + 512);
            f16x8 w2 = *(const f16x8*)(wb + 1024);
            f16x8 w3 = *(const f16x8*)(wb + 1536);
            acc0 = __builtin_amdgcn_mfma_f32_32x32x16_f16(axa, w0, acc0, 0, 0, 0);
            acc1 = __builtin_amdgcn_mfma_f32_32x32x16_f16(axa, w1, acc1, 0, 0, 0);
            acc2 = __builtin_amdgcn_mfma_f32_32x32x16_f16(axa, w2, acc2, 0, 0, 0);
            acc3 = __builtin_amdgcn_mfma_f32_32x32x16_f16(axa, w3, acc3, 0, 0, 0);
            acc4 = __builtin_amdgcn_mfma_f32_32x32x16_f16(axb, w0, acc4, 0, 0, 0);
            acc5 = __builtin_amdgcn_mfma_f32_32x32x16_f16(axb, w1, acc5, 0, 0, 0);
            acc6 = __builtin_amdgcn_mfma_f32_32x32x16_f16(axb, w2, acc6, 0, 0, 0);
            acc7 = __builtin_amdgcn_mfma_f32_32x32x16_f16(axb, w3, acc7, 0, 0, 0);
        }
    }

    // ---- cross-wave O reduction, two sequential passes over the same LDS ----
    float bv0 = bias[h * 128 + l31];
    float bv1 = bias[h * 128 + 32 + l31];
    float bv2 = bias[h * 128 + 64 + l31];
    float bv3 = bias[h * 128 + 96 + l31];

    #pragma unroll
    for (int pass = 0; pass < 2; pass++) {
        f32x16 p0 = pass ? acc4 : acc0;
        f32x16 p1 = pass ? acc5 : acc1;
        f32x16 p2 = pass ? acc6 : acc2;
        f32x16 p3 = pass ? acc7 : acc3;
        int rbase = i0 + pass * 32;
        __syncthreads();
        if (w >= 2) {
            float* dp = xred[w - 2] + lane * 68;
            PUTACC(dp, 0, p0); PUTACC(dp, 16, p1); PUTACC(dp, 32, p2); PUTACC(dp, 48, p3);
        }
        __syncthreads();
        if (w < 2) {
            const float* dp = xred[w] + lane * 68;
            ADDACC(dp, 0, p0); ADDACC(dp, 16, p1); ADDACC(dp, 32, p2); ADDACC(dp, 48, p3);
        }
        __syncthreads();
        if (w == 1) {
            float* dp = xred[0] + lane * 68;
            PUTACC(dp, 0, p0); PUTACC(dp, 16, p1); PUTACC(dp, 32, p2); PUTACC(dp, 48, p3);
        }
        __syncthreads();
        if (w == 0) {
            const float* dp = xred[0] + lane * 68;
            ADDACC(dp, 0, p0); ADDACC(dp, 16, p1); ADDACC(dp, 32, p2); ADDACC(dp, 48, p3);
            #pragma unroll
            for (int r = 0; r < 16; r++) {
                int row = rbase + (r & 3) + 8 * (r >> 2) + 4 * half;
                float* op = out + (size_t)row * 1024 + h * 128 + l31;
                op[0]  = p0[r] + bv0;
                op[32] = p1[r] + bv1;
                op[64] = p2[r] + bv2;
                op[96] = p3[r] + bv3;
            }
        }
    }
}

extern "C" void kernel_launch(void* const* d_in, const int* in_sizes, int n_in,
                              void* d_out, int out_size, void* d_ws, size_t ws_size,
                              hipStream_t stream) {
    (void)in_sizes; (void)n_in; (void)out_size; (void)ws_size;
    const float* x     = (const float*)d_in[0];
    const int*   graph = (const int*)d_in[1];
    const float* W     = (const float*)d_in[2];
    const float* wi    = (const float*)d_in[3];
    const float* wj    = (const float*)d_in[4];
    const float* Wr    = (const float*)d_in[5];
    const float* bias  = (const float*)d_in[6];
    float* out = (float*)d_out;

    char* ws = (char*)d_ws;
    unsigned int* maskJ = (unsigned int*)ws;              // 2 MB  [128 jw][4096 i]
    f16* hbT2  = (f16*)(ws + (2u << 20));                 // 8 MB  [8][(j>>4)*128+f][j&15]
    f16* Wht2  = (f16*)(ws + (10u << 20));                // 1 MB  swizzled
    f16* Wrt2  = (f16*)(ws + (11u << 20));                // 1 MB  swizzled
    f16* xh2   = (f16*)(ws + (12u << 20));                // 4 MB  [32][4096][16] swizzled
    float* a2    = (float*)(ws + (16u << 20));            // 128 KB
    float* b2    = a2 + 8 * 4096;
    float* ABpre = b2 + 8 * 4096;
    float* Bpre  = ABpre + 2 * 8 * 4096;
    unsigned int* M2e = (unsigned int*)(Bpre + 2 * 8 * 4096);

    hipLaunchKernelGGL(k_mask, dim3(1024), dim3(256), 0, stream, graph, maskJ, M2e);
    hipLaunchKernelGGL(k_pre, dim3(1536), dim3(256), 0, stream, x, xh2, W, Wht2, Wr, Wrt2);
    hipLaunchKernelGGL(k_gemm_h, dim3(1024), dim3(256), 0, stream, xh2, Wht2, hbT2,
                       wi, wj, a2, b2, M2e);
    hipLaunchKernelGGL(k_prep, dim3(128), dim3(256), 0, stream, a2, b2, M2e, ABpre, Bpre);
    hipLaunchKernelGGL(k_main, dim3(512), dim3(256), 0, stream, xh2, hbT2, Wrt2, maskJ,
                       ABpre, Bpre, bias, out);
}

// Round 13
// 232.962 us; speedup vs baseline: 1.0743x; 1.0743x over previous
//
#include <hip/hip_runtime.h>
#include <hip/hip_fp16.h>

typedef _Float16 f16;
typedef _Float16 f16x8 __attribute__((ext_vector_type(8)));
typedef _Float16 f16x2v __attribute__((ext_vector_type(2)));
typedef __fp16 h16x2 __attribute__((ext_vector_type(2)));
typedef float f32x4 __attribute__((ext_vector_type(4)));
typedef float f32x16 __attribute__((ext_vector_type(16)));

#define LOG2E 1.4426950408889634f
#define NSL 0.2f

// ---------------- Kernel 1: graph -> j-major transposed bitmask (+ init M2e) ----------------
__global__ __launch_bounds__(256) void k_mask(const int* __restrict__ graph,
                                              unsigned int* __restrict__ maskJ,
                                              unsigned int* __restrict__ M2e) {
    if (blockIdx.x == 0 && threadIdx.x < 8) M2e[threadIdx.x] = 0x007FFFFFu;  // enc(-inf)
    __shared__ unsigned long long bal[4][64];
    int w = threadIdx.x >> 6;
    int lane = threadIdx.x & 63;
    int gw = blockIdx.x * 4 + w;
    int ti = gw & 63, tj = gw >> 6;
    int i0 = ti * 64, j0 = tj * 64;
    #pragma unroll 8
    for (int k = 0; k < 64; k++) {
        int g = graph[(j0 + k) * 4096 + i0 + lane];
        unsigned long long b = __ballot(g > 0);
        if (lane == 0) bal[w][k] = b;
    }
    __syncthreads();
    unsigned long long word = 0;
    #pragma unroll 8
    for (int k = 0; k < 64; k++) {
        word |= ((bal[w][k] >> lane) & 1ull) << k;
    }
    int jw = j0 >> 5;
    maskJ[(size_t)jw * 4096 + i0 + lane]       = (unsigned int)word;
    maskJ[(size_t)(jw + 1) * 4096 + i0 + lane] = (unsigned int)(word >> 32);
}

// ---------------- Kernel 2 (fused prep): xcvt + swizzled weight transposes ----------------
__device__ void dev_transpose_sw(const float* __restrict__ in, f16* __restrict__ out,
                                 int C, int S, int bxx, int byy, int tid) {
    __shared__ float tile[32][33];
    int tx = tid & 31, ty = tid >> 5;
    int c0 = bxx * 32, r0 = byy * 32;
    for (int rr = ty; rr < 32; rr += 8)
        tile[rr][tx] = in[(r0 + rr) * C + c0 + tx];
    __syncthreads();
    for (int rr = ty; rr < 32; rr += 8) {
        int m = r0 + tx, f = c0 + rr;
        out[(size_t)((m >> 4) * S + f) * 16 + (m & 15)] = (f16)tile[tx][rr];
    }
}

__global__ __launch_bounds__(256) void k_pre(const float* __restrict__ x,
                                             f16* __restrict__ xh2,
                                             const float* __restrict__ W,
                                             f16* __restrict__ Wht2,
                                             const float* __restrict__ Wr,
                                             f16* __restrict__ Wrt2) {
    int bx = blockIdx.x;
    int tid = threadIdx.x;
    if (bx < 512) {
        int id = bx * 256 + tid;   // 131072
        int row = id & 4095, kt = id >> 12;
        const float4* xs = (const float4*)(x + (size_t)row * 512 + kt * 16);
        float4 u0 = xs[0], u1 = xs[1], u2 = xs[2], u3 = xs[3];
        union { int4 a[2]; h16x2 p[8]; } px;
        px.p[0] = __builtin_amdgcn_cvt_pkrtz(u0.x, u0.y);
        px.p[1] = __builtin_amdgcn_cvt_pkrtz(u0.z, u0.w);
        px.p[2] = __builtin_amdgcn_cvt_pkrtz(u1.x, u1.y);
        px.p[3] = __builtin_amdgcn_cvt_pkrtz(u1.z, u1.w);
        px.p[4] = __builtin_amdgcn_cvt_pkrtz(u2.x, u2.y);
        px.p[5] = __builtin_amdgcn_cvt_pkrtz(u2.z, u2.w);
        px.p[6] = __builtin_amdgcn_cvt_pkrtz(u3.x, u3.y);
        px.p[7] = __builtin_amdgcn_cvt_pkrtz(u3.z, u3.w);
        int4* d = (int4*)(xh2 + ((size_t)kt * 4096 + row) * 16);
        d[0] = px.a[0]; d[1] = px.a[1];
    } else if (bx < 1024) {
        int id = bx - 512;                       // W -> Wht2
        dev_transpose_sw(W, Wht2, 128, 128, id & 3, id >> 2, tid);
    } else {
        int id = bx - 1024;                      // Wr -> Wrt2
        dev_transpose_sw(Wr, Wrt2, 1024, 1024, id & 31, id >> 5, tid);
    }
}

// ---------------- Kernel 3: hbT2 + fused a2/b2 + per-head max ----------------
__global__ __launch_bounds__(256, 4) void k_gemm_h(const f16* __restrict__ xh2,
                                                   const f16* __restrict__ Wht2,
                                                   f16* __restrict__ hbT2,
                                                   const float* __restrict__ wi,
                                                   const float* __restrict__ wj,
                                                   float* __restrict__ a2,
                                                   float* __restrict__ b2,
                                                   unsigned int* __restrict__ M2e) {
    __shared__ float swi[128], swj[128];
    __shared__ float pwa[4][32], pwb[4][32];
    int bx = blockIdx.x;
    int h = bx & 7, jb = bx >> 3;        // 128 j-tiles of 32
    int j0 = jb * 32;
    int tid = threadIdx.x;
    int w = tid >> 6, lane = tid & 63;
    int ln = lane & 15, q = lane >> 4;
    if (tid < 128) { swi[tid] = wi[h * 128 + tid]; swj[tid] = wj[h * 128 + tid]; }
    __syncthreads();

    int ko = (q & 1) * 8;
    const f16* pa = Wht2 + ((size_t)(h * 512) * 8 + (size_t)(q >> 1) * 128 + w * 32 + ln) * 16 + ko;
    const f16* pb = xh2 + ((size_t)(q >> 1) * 4096 + j0 + ln) * 16 + ko;

    f32x4 acc00 = {}, acc01 = {}, acc10 = {}, acc11 = {};

    f16x8 ra0 = *(const f16x8*)(pa);
    f16x8 ra1 = *(const f16x8*)(pa + 256);
    f16x8 rb0 = *(const f16x8*)(pb);
    f16x8 rb1 = *(const f16x8*)(pb + 256);

    for (int kk = 0; kk < 8; kk++) {
        f16x8 sa0 = *(const f16x8*)(pa + 4096);
        f16x8 sa1 = *(const f16x8*)(pa + 4096 + 256);
        f16x8 sb0 = *(const f16x8*)(pb + 131072);
        f16x8 sb1 = *(const f16x8*)(pb + 131072 + 256);
        acc00 = __builtin_amdgcn_mfma_f32_16x16x32_f16(ra0, rb0, acc00, 0, 0, 0);
        acc01 = __builtin_amdgcn_mfma_f32_16x16x32_f16(ra0, rb1, acc01, 0, 0, 0);
        acc10 = __builtin_amdgcn_mfma_f32_16x16x32_f16(ra1, rb0, acc10, 0, 0, 0);
        acc11 = __builtin_amdgcn_mfma_f32_16x16x32_f16(ra1, rb1, acc11, 0, 0, 0);
        pa += 8192; pb += 262144;
        ra0 = *(const f16x8*)(pa);
        ra1 = *(const f16x8*)(pa + 256);
        rb0 = *(const f16x8*)(pb);
        rb1 = *(const f16x8*)(pb + 256);
        acc00 = __builtin_amdgcn_mfma_f32_16x16x32_f16(sa0, sb0, acc00, 0, 0, 0);
        acc01 = __builtin_amdgcn_mfma_f32_16x16x32_f16(sa0, sb1, acc01, 0, 0, 0);
        acc10 = __builtin_amdgcn_mfma_f32_16x16x32_f16(sa1, sb0, acc10, 0, 0, 0);
        acc11 = __builtin_amdgcn_mfma_f32_16x16x32_f16(sa1, sb1, acc11, 0, 0, 0);
    }

    size_t hb = (size_t)h * 524288 + (size_t)(j0 >> 4) * 2048;
    #pragma unroll
    for (int r = 0; r < 4; r++) {
        int f0 = w * 32 + q * 4 + r;
        hbT2[hb + f0 * 16 + ln]                 = (f16)acc00[r];
        hbT2[hb + 2048 + f0 * 16 + ln]          = (f16)acc01[r];
        hbT2[hb + (f0 + 16) * 16 + ln]          = (f16)acc10[r];
        hbT2[hb + 2048 + (f0 + 16) * 16 + ln]   = (f16)acc11[r];
    }

    float pa0 = 0.f, pb0 = 0.f, pa1 = 0.f, pb1 = 0.f;
    #pragma unroll
    for (int r = 0; r < 4; r++) {
        int f0 = w * 32 + q * 4 + r;
        float w0 = swi[f0], jv0 = swj[f0];
        float w1 = swi[f0 + 16], jv1 = swj[f0 + 16];
        pa0 += acc00[r] * w0 + acc10[r] * w1;
        pb0 += acc00[r] * jv0 + acc10[r] * jv1;
        pa1 += acc01[r] * w0 + acc11[r] * w1;
        pb1 += acc01[r] * jv0 + acc11[r] * jv1;
    }
    pa0 += __shfl_xor(pa0, 16); pa0 += __shfl_xor(pa0, 32);
    pb0 += __shfl_xor(pb0, 16); pb0 += __shfl_xor(pb0, 32);
    pa1 += __shfl_xor(pa1, 16); pa1 += __shfl_xor(pa1, 32);
    pb1 += __shfl_xor(pb1, 16); pb1 += __shfl_xor(pb1, 32);
    if (lane < 16) {
        pwa[w][ln] = pa0;      pwb[w][ln] = pb0;
        pwa[w][16 + ln] = pa1; pwb[w][16 + ln] = pb1;
    }
    __syncthreads();
    if (tid < 32) {
        int jj = tid;
        float pav = (pwa[0][jj] + pwa[1][jj]) + (pwa[2][jj] + pwa[3][jj]);
        float pbv = (pwb[0][jj] + pwb[1][jj]) + (pwb[2][jj] + pwb[3][jj]);
        a2[h * 4096 + j0 + jj] = pav * LOG2E;
        float bb = pbv * LOG2E;
        b2[h * 4096 + j0 + jj] = bb;
        float m = bb;
        m = fmaxf(m, __shfl_xor(m, 1, 32));
        m = fmaxf(m, __shfl_xor(m, 2, 32));
        m = fmaxf(m, __shfl_xor(m, 4, 32));
        m = fmaxf(m, __shfl_xor(m, 8, 32));
        m = fmaxf(m, __shfl_xor(m, 16, 32));
        if (jj == 0) {
            unsigned u = __float_as_uint(m);
            unsigned enc = (u & 0x80000000u) ? ~u : (u | 0x80000000u);
            atomicMax(&M2e[h], enc);
        }
    }
}

// ---------------- Kernel 5: packed f16x2 exp tables (M2 folded into B; all values <= 1) ----------------
// ABp2[i] = {2^(u-m2), 2^(.2u-m2)}, u = a2+M2, m2 = lrelu(u)
// Bp2[j]  = {2^(t), 2^(.2t)}, t = b2-M2  (<= 0)
__global__ __launch_bounds__(256) void k_prep(const float* __restrict__ a2,
                                              const float* __restrict__ b2,
                                              const unsigned int* __restrict__ M2e,
                                              unsigned int* __restrict__ ABp2,
                                              unsigned int* __restrict__ Bp2) {
    int id = blockIdx.x * 256 + threadIdx.x;   // 32768
    int h = id >> 12;
    unsigned enc = M2e[h];
    unsigned u = (enc & 0x80000000u) ? (enc & 0x7FFFFFFFu) : ~enc;
    float M2 = __uint_as_float(u);
    float av = a2[id];
    float uu = av + M2;
    float m2 = fmaxf(uu, NSL * uu);
    union { h16x2 p; unsigned int i; } pa, pb;
    pa.p = __builtin_amdgcn_cvt_pkrtz(exp2f(uu - m2), exp2f(NSL * uu - m2));
    ABp2[id] = pa.i;
    float tb = b2[id] - M2;
    pb.p = __builtin_amdgcn_cvt_pkrtz(exp2f(tb), exp2f(NSL * tb));
    Bp2[id] = pb.i;
}

// ---------------- Kernel 6 helpers ----------------
// packed PGEN over 8 j: bq0/bq1 = 8 uints (each = {B,B'} f16x2). Ap = {A1,A2} f16x2.
#define PGENP(afv, m8, bq0, bq1)                                                     \
    {                                                                                \
        union { int4 i4; unsigned u[4]; } ua, ub;                                    \
        ua.i4 = (bq0); ub.i4 = (bq1);                                                \
        f16x2v dacc = {(_Float16)0, (_Float16)0};                                    \
        _Float16 z = (_Float16)0;                                                    \
        _Float16 p0, p1;                                                             \
        f16x2v m0, m1;                                                               \
        union { unsigned u; f16x2v v; } cv0, cv1;                                    \
        cv0.u = ua.u[0]; cv1.u = ua.u[1];                                            \
        m0 = Ap * cv0.v; m1 = Ap * cv1.v;                                            \
        p0 = m0.x >= m0.y ? m0.x : m0.y;  p1 = m1.x >= m1.y ? m1.x : m1.y;           \
        p0 = ((m8) & 1u) ? p0 : z;        p1 = ((m8) & 2u) ? p1 : z;                 \
        afv.p[0].x = p0; afv.p[0].y = p1; dacc += afv.p[0];                          \
        cv0.u = ua.u[2]; cv1.u = ua.u[3];                                            \
        m0 = Ap * cv0.v; m1 = Ap * cv1.v;                                            \
        p0 = m0.x >= m0.y ? m0.x : m0.y;  p1 = m1.x >= m1.y ? m1.x : m1.y;           \
        p0 = ((m8) & 4u) ? p0 : z;        p1 = ((m8) & 8u) ? p1 : z;                 \
        afv.p[1].x = p0; afv.p[1].y = p1; dacc += afv.p[1];                          \
        cv0.u = ub.u[0]; cv1.u = ub.u[1];                                            \
        m0 = Ap * cv0.v; m1 = Ap * cv1.v;                                            \
        p0 = m0.x >= m0.y ? m0.x : m0.y;  p1 = m1.x >= m1.y ? m1.x : m1.y;           \
        p0 = ((m8) & 16u) ? p0 : z;       p1 = ((m8) & 32u) ? p1 : z;                \
        afv.p[2].x = p0; afv.p[2].y = p1; dacc += afv.p[2];                          \
        cv0.u = ub.u[2]; cv1.u = ub.u[3];                                            \
        m0 = Ap * cv0.v; m1 = Ap * cv1.v;                                            \
        p0 = m0.x >= m0.y ? m0.x : m0.y;  p1 = m1.x >= m1.y ? m1.x : m1.y;           \
        p0 = ((m8) & 64u) ? p0 : z;       p1 = ((m8) & 128u) ? p1 : z;               \
        afv.p[3].x = p0; afv.p[3].y = p1; dacc += afv.p[3];                          \
        dsum += (float)dacc.x + (float)dacc.y;                                       \
    }

#define PUTACC(dp, off, accv)                                                    \
    {                                                                            \
        union { f32x16 v; f32x4 q[4]; } t; t.v = (accv);                         \
        *(f32x4*)((dp) + (off))      = t.q[0];                                   \
        *(f32x4*)((dp) + (off) + 4)  = t.q[1];                                   \
        *(f32x4*)((dp) + (off) + 8)  = t.q[2];                                   \
        *(f32x4*)((dp) + (off) + 12) = t.q[3];                                   \
    }

#define ADDACC(dp, off, accv)                                                    \
    {                                                                            \
        union { f32x16 v; f32x4 q[4]; } t; t.v = (accv);                         \
        t.q[0] += *(const f32x4*)((dp) + (off));                                 \
        t.q[1] += *(const f32x4*)((dp) + (off) + 4);                             \
        t.q[2] += *(const f32x4*)((dp) + (off) + 8);                             \
        t.q[3] += *(const f32x4*)((dp) + (off) + 12);                            \
        (accv) = t.v;                                                            \
    }

// ---------------- Kernel 6: main — LDS-staged Bpre/mask (zero in-loop global latency on
// P-gen inputs), packed-f16 PGEN, frag reg dbuf. 4 waves/SIMD. ----------------
__global__ __launch_bounds__(256, 4) void k_main(const f16* __restrict__ xh2,
                                                 const f16* __restrict__ hbT2,
                                                 const f16* __restrict__ Wrt2,
                                                 const unsigned int* __restrict__ maskJ,
                                                 const unsigned int* __restrict__ ABp2,
                                                 const unsigned int* __restrict__ Bp2,
                                                 const float* __restrict__ bias,
                                                 float* __restrict__ out) {
    __shared__ char smem[35328];          // [0,16512) mask[32][129] | [16512,32896) Bpre[4096]
                                          // (both dead after loop; xred[2][64*68] aliases [0,34816))
    __shared__ float dred[128];

    unsigned int* mlds = (unsigned int*)smem;
    unsigned int* blds = (unsigned int*)(smem + 16512);

    int bx = blockIdx.x;
    int h = bx & 7, it = bx >> 3;
    int i0 = it * 32;
    int tid = threadIdx.x;
    int w = tid >> 6, lane = tid & 63;
    int l31 = lane & 31, half = lane >> 5;
    int i = i0 + l31;

    // ---- stage Bpre table (4096 uints) and mask strip (32 i x 128 words) into LDS ----
    {
        const int4* bsrc = (const int4*)(Bp2 + h * 4096);
        int4* bdst = (int4*)blds;
        #pragma unroll
        for (int c = 0; c < 4; c++) bdst[tid + c * 256] = bsrc[tid + c * 256];
        #pragma unroll
        for (int c = 0; c < 16; c++) {
            int e = tid + c * 256;                 // e = jw*32 + i
            int jw = e >> 5, ii = e & 31;
            mlds[ii * 129 + jw] = maskJ[(size_t)jw * 4096 + i0 + ii];
        }
    }

    union { unsigned u; f16x2v v; } apc;
    apc.u = ABp2[h * 4096 + i];
    f16x2v Ap = apc.v;

    f32x16 acc0 = {}, acc1 = {}, acc2 = {}, acc3 = {};
    float dsum = 0.f;

    int J0 = w * 1024;
    const f16* bb = hbT2 + (size_t)h * 524288 + ((size_t)(J0 >> 4) * 128 + l31) * 16 + half * 8;
    const unsigned int* bp0 = blds + J0 + half * 8;    // wave-uniform per half -> broadcast reads
    const unsigned int* mrow = mlds + l31 * 129 + (J0 >> 5);

    int sh0 = half << 3;
    int sh1 = 16 + (half << 3);

    __syncthreads();

    // prologue: frags + Bpre for tile 0, mask word for pair 0
    f16x8 fa0 = *(const f16x8*)(bb);
    f16x8 fa1 = *(const f16x8*)(bb + 512);
    f16x8 fa2 = *(const f16x8*)(bb + 1024);
    f16x8 fa3 = *(const f16x8*)(bb + 1536);
    int4 qa0 = ((const int4*)(bp0))[0];
    int4 qa1 = ((const int4*)(bp0))[1];
    unsigned mwc = mrow[0];

    for (int tp = 0; tp < 32; tp++) {
        int t0 = tp * 2;
        // prefetch odd tile (frags from L2, Bpre from LDS), next-pair mask
        const f16* s1 = bb + (size_t)(t0 + 1) * 2048;
        f16x8 fb0 = *(const f16x8*)(s1);
        f16x8 fb1 = *(const f16x8*)(s1 + 512);
        f16x8 fb2 = *(const f16x8*)(s1 + 1024);
        f16x8 fb3 = *(const f16x8*)(s1 + 1536);
        const unsigned int* bpn = bp0 + (t0 + 1) * 16;
        int4 qb0 = ((const int4*)(bpn))[0];
        int4 qb1 = ((const int4*)(bpn))[1];
        unsigned mwn = mrow[tp + 1];

        // body even t0
        {
            union { f16x8 v; f16x2v p[4]; } af;
            PGENP(af, mwc >> sh0, qa0, qa1);
            acc0 = __builtin_amdgcn_mfma_f32_32x32x16_f16(af.v, fa0, acc0, 0, 0, 0);
            acc1 = __builtin_amdgcn_mfma_f32_32x32x16_f16(af.v, fa1, acc1, 0, 0, 0);
            acc2 = __builtin_amdgcn_mfma_f32_32x32x16_f16(af.v, fa2, acc2, 0, 0, 0);
            acc3 = __builtin_amdgcn_mfma_f32_32x32x16_f16(af.v, fa3, acc3, 0, 0, 0);
        }

        // prefetch next even tile (last-iter overrun stays inside workspace / LDS block)
        const f16* s2 = bb + (size_t)(t0 + 2) * 2048;
        fa0 = *(const f16x8*)(s2);
        fa1 = *(const f16x8*)(s2 + 512);
        fa2 = *(const f16x8*)(s2 + 1024);
        fa3 = *(const f16x8*)(s2 + 1536);
        const unsigned int* bpn2 = bp0 + (t0 + 2) * 16;
        qa0 = ((const int4*)(bpn2))[0];
        qa1 = ((const int4*)(bpn2))[1];

        // body odd t0+1
        {
            union { f16x8 v; f16x2v p[4]; } af;
            PGENP(af, mwc >> sh1, qb0, qb1);
            acc0 = __builtin_amdgcn_mfma_f32_32x32x16_f16(af.v, fb0, acc0, 0, 0, 0);
            acc1 = __builtin_amdgcn_mfma_f32_32x32x16_f16(af.v, fb1, acc1, 0, 0, 0);
            acc2 = __builtin_amdgcn_mfma_f32_32x32x16_f16(af.v, fb2, acc2, 0, 0, 0);
            acc3 = __builtin_amdgcn_mfma_f32_32x32x16_f16(af.v, fb3, acc3, 0, 0, 0);
        }
        mwc = mwn;
    }

    // ---- denominator: combine j-halves in-wave, then cross-wave via LDS ----
    dsum += __shfl(dsum, lane ^ 32);
    if (lane < 32) dred[w * 32 + l31] = dsum;
    __syncthreads();
    {
        #pragma unroll
        for (int r = 0; r < 16; r++) {
            int row = (r & 3) + 8 * (r >> 2) + 4 * half;
            float s = dred[row] + dred[32 + row] + dred[64 + row] + dred[96 + row];
            float inv = 1.0f / s;
            acc0[r] *= inv; acc1[r] *= inv; acc2[r] *= inv; acc3[r] *= inv;
        }
    }

    // ---- residual: acc += x @ Wr[:, h-slice]; k-quarter per wave ----
    {
        #pragma unroll
        for (int kt = 0; kt < 8; kt++) {
            int ktt = w * 8 + kt;
            f16x8 ax = *(const f16x8*)(xh2 + ((size_t)ktt * 4096 + i) * 16 + half * 8);
            const f16* wb = Wrt2 + ((size_t)ktt * 1024 + h * 128 + l31) * 16 + half * 8;
            acc0 = __builtin_amdgcn_mfma_f32_32x32x16_f16(ax, *(const f16x8*)(wb), acc0, 0, 0, 0);
            acc1 = __builtin_amdgcn_mfma_f32_32x32x16_f16(ax, *(const f16x8*)(wb + 512), acc1, 0, 0, 0);
            acc2 = __builtin_amdgcn_mfma_f32_32x32x16_f16(ax, *(const f16x8*)(wb + 1024), acc2, 0, 0, 0);
            acc3 = __builtin_amdgcn_mfma_f32_32x32x16_f16(ax, *(const f16x8*)(wb + 1536), acc3, 0, 0, 0);
        }
    }

    // ---- cross-wave O reduction (xred aliases staging LDS, dead since loop end) ----
    float* xredb = (float*)smem;
    __syncthreads();   // dred reads done; smem reusable
    if (w >= 2) {
        float* dp = xredb + (w - 2) * 4352 + lane * 68;
        PUTACC(dp, 0, acc0); PUTACC(dp, 16, acc1); PUTACC(dp, 32, acc2); PUTACC(dp, 48, acc3);
    }
    __syncthreads();
    if (w < 2) {
        const float* dp = xredb + w * 4352 + lane * 68;
        ADDACC(dp, 0, acc0); ADDACC(dp, 16, acc1); ADDACC(dp, 32, acc2); ADDACC(dp, 48, acc3);
    }
    __syncthreads();
    if (w == 1) {
        float* dp = xredb + lane * 68;
        PUTACC(dp, 0, acc0); PUTACC(dp, 16, acc1); PUTACC(dp, 32, acc2); PUTACC(dp, 48, acc3);
    }
    __syncthreads();
    if (w == 0) {
        const float* dp = xredb + lane * 68;
        ADDACC(dp, 0, acc0); ADDACC(dp, 16, acc1); ADDACC(dp, 32, acc2); ADDACC(dp, 48, acc3);
        #pragma unroll
        for (int n = 0; n < 4; n++) {
            union { f32x16 v; f32x4 q[4]; } t;
            t.v = (n == 0) ? acc0 : (n == 1) ? acc1 : (n == 2) ? acc2 : acc3;
            int col = h * 128 + n * 32 + l31;
            float bv = bias[col];
            #pragma unroll
            for (int r = 0; r < 16; r++) {
                int row = i0 + (r & 3) + 8 * (r >> 2) + 4 * half;
                out[(size_t)row * 1024 + col] = t.v[r] + bv;
            }
        }
    }
}

extern "C" void kernel_launch(void* const* d_in, const int* in_sizes, int n_in,
                              void* d_out, int out_size, void* d_ws, size_t ws_size,
                              hipStream_t stream) {
    (void)in_sizes; (void)n_in; (void)out_size; (void)ws_size;
    const float* x     = (const float*)d_in[0];
    const int*   graph = (const int*)d_in[1];
    const float* W     = (const float*)d_in[2];
    const float* wi    = (const float*)d_in[3];
    const float* wj    = (const float*)d_in[4];
    const float* Wr    = (const float*)d_in[5];
    const float* bias  = (const float*)d_in[6];
    float* out = (float*)d_out;

    char* ws = (char*)d_ws;
    unsigned int* maskJ = (unsigned int*)ws;              // 2 MB  [128 jw][4096 i]
    f16* hbT2  = (f16*)(ws + (2u << 20));                 // 8 MB  [8][(j>>4)*128+f][j&15]
    f16* Wht2  = (f16*)(ws + (10u << 20));                // 1 MB  swizzled
    f16* Wrt2  = (f16*)(ws + (11u << 20));                // 1 MB  swizzled
    f16* xh2   = (f16*)(ws + (12u << 20));                // 4 MB  [32][4096][16] swizzled
    float* a2    = (float*)(ws + (16u << 20));            // 128 KB
    float* b2    = a2 + 8 * 4096;                         // 128 KB
    unsigned int* ABp2 = (unsigned int*)(b2 + 8 * 4096);  // 128 KB packed f16x2
    unsigned int* Bp2  = ABp2 + 8 * 4096;                 // 128 KB packed f16x2
    unsigned int* M2e  = Bp2 + 8 * 4096;                  // 32 B

    hipLaunchKernelGGL(k_mask, dim3(1024), dim3(256), 0, stream, graph, maskJ, M2e);
    hipLaunchKernelGGL(k_pre, dim3(1536), dim3(256), 0, stream, x, xh2, W, Wht2, Wr, Wrt2);
    hipLaunchKernelGGL(k_gemm_h, dim3(1024), dim3(256), 0, stream, xh2, Wht2, hbT2,
                       wi, wj, a2, b2, M2e);
    hipLaunchKernelGGL(k_prep, dim3(128), dim3(256), 0, stream, a2, b2, M2e, ABp2, Bp2);
    hipLaunchKernelGGL(k_main, dim3(1024), dim3(256), 0, stream, xh2, hbT2, Wrt2, maskJ,
                       ABp2, Bp2, bias, out);
}

// Round 14
// 227.386 us; speedup vs baseline: 1.1007x; 1.0245x over previous
//
#include <hip/hip_runtime.h>
#include <hip/hip_fp16.h>

typedef _Float16 f16;
typedef _Float16 f16x8 __attribute__((ext_vector_type(8)));
typedef _Float16 f16x2v __attribute__((ext_vector_type(2)));
typedef __fp16 h16x2 __attribute__((ext_vector_type(2)));
typedef float f32x4 __attribute__((ext_vector_type(4)));
typedef float f32x16 __attribute__((ext_vector_type(16)));

#define LOG2E 1.4426950408889634f
#define NSL 0.2f

// ---------------- Kernel 1 (fused): graph->bitmask (blocks 0..1023) + xcvt/transposes ----------------
__global__ __launch_bounds__(256) void k_pre(const int* __restrict__ graph,
                                             unsigned int* __restrict__ maskJ,
                                             unsigned int* __restrict__ M2e,
                                             const float* __restrict__ x,
                                             f16* __restrict__ xh2,
                                             const float* __restrict__ W,
                                             f16* __restrict__ Wht2,
                                             const float* __restrict__ Wr,
                                             f16* __restrict__ Wrt2) {
    __shared__ unsigned long long bal[4][64];
    __shared__ float tile[32][33];
    int bx = blockIdx.x;
    int tid = threadIdx.x;
    if (bx < 1024) {
        // ---- mask part ----
        if (bx == 0 && tid < 8) M2e[tid] = 0x007FFFFFu;  // enc(-inf)
        int w = tid >> 6;
        int lane = tid & 63;
        int gw = bx * 4 + w;
        int ti = gw & 63, tj = gw >> 6;
        int i0 = ti * 64, j0 = tj * 64;
        #pragma unroll 8
        for (int k = 0; k < 64; k++) {
            int g = graph[(j0 + k) * 4096 + i0 + lane];
            unsigned long long b = __ballot(g > 0);
            if (lane == 0) bal[w][k] = b;
        }
        __syncthreads();
        unsigned long long word = 0;
        #pragma unroll 8
        for (int k = 0; k < 64; k++) {
            word |= ((bal[w][k] >> lane) & 1ull) << k;
        }
        int jw = j0 >> 5;
        maskJ[(size_t)jw * 4096 + i0 + lane]       = (unsigned int)word;
        maskJ[(size_t)(jw + 1) * 4096 + i0 + lane] = (unsigned int)(word >> 32);
    } else if (bx < 1536) {
        // ---- x fp32 -> f16 swizzled ----
        int id = (bx - 1024) * 256 + tid;   // 131072
        int row = id & 4095, kt = id >> 12;
        const float4* xs = (const float4*)(x + (size_t)row * 512 + kt * 16);
        float4 u0 = xs[0], u1 = xs[1], u2 = xs[2], u3 = xs[3];
        union { int4 a[2]; h16x2 p[8]; } px;
        px.p[0] = __builtin_amdgcn_cvt_pkrtz(u0.x, u0.y);
        px.p[1] = __builtin_amdgcn_cvt_pkrtz(u0.z, u0.w);
        px.p[2] = __builtin_amdgcn_cvt_pkrtz(u1.x, u1.y);
        px.p[3] = __builtin_amdgcn_cvt_pkrtz(u1.z, u1.w);
        px.p[4] = __builtin_amdgcn_cvt_pkrtz(u2.x, u2.y);
        px.p[5] = __builtin_amdgcn_cvt_pkrtz(u2.z, u2.w);
        px.p[6] = __builtin_amdgcn_cvt_pkrtz(u3.x, u3.y);
        px.p[7] = __builtin_amdgcn_cvt_pkrtz(u3.z, u3.w);
        int4* d = (int4*)(xh2 + ((size_t)kt * 4096 + row) * 16);
        d[0] = px.a[0]; d[1] = px.a[1];
    } else {
        // ---- weight transposes into MFMA-fragment layout ----
        const float* in; f16* out; int C, S, bxx, byy;
        if (bx < 2048) { int id = bx - 1536; in = W;  out = Wht2; C = 128;  S = 128;  bxx = id & 3;  byy = id >> 2; }
        else           { int id = bx - 2048; in = Wr; out = Wrt2; C = 1024; S = 1024; bxx = id & 31; byy = id >> 5; }
        int tx = tid & 31, ty = tid >> 5;
        int c0 = bxx * 32, r0 = byy * 32;
        for (int rr = ty; rr < 32; rr += 8)
            tile[rr][tx] = in[(r0 + rr) * C + c0 + tx];
        __syncthreads();
        for (int rr = ty; rr < 32; rr += 8) {
            int m = r0 + tx, f = c0 + rr;
            out[(size_t)((m >> 4) * S + f) * 16 + (m & 15)] = (f16)tile[tx][rr];
        }
    }
}

// ---------------- Kernel 3: hbT2 + fused a2/b2 + per-head max ----------------
__global__ __launch_bounds__(256, 4) void k_gemm_h(const f16* __restrict__ xh2,
                                                   const f16* __restrict__ Wht2,
                                                   f16* __restrict__ hbT2,
                                                   const float* __restrict__ wi,
                                                   const float* __restrict__ wj,
                                                   float* __restrict__ a2,
                                                   float* __restrict__ b2,
                                                   unsigned int* __restrict__ M2e) {
    __shared__ float swi[128], swj[128];
    __shared__ float pwa[4][32], pwb[4][32];
    int bx = blockIdx.x;
    int h = bx & 7, jb = bx >> 3;        // 128 j-tiles of 32
    int j0 = jb * 32;
    int tid = threadIdx.x;
    int w = tid >> 6, lane = tid & 63;
    int ln = lane & 15, q = lane >> 4;
    if (tid < 128) { swi[tid] = wi[h * 128 + tid]; swj[tid] = wj[h * 128 + tid]; }
    __syncthreads();

    int ko = (q & 1) * 8;
    const f16* pa = Wht2 + ((size_t)(h * 512) * 8 + (size_t)(q >> 1) * 128 + w * 32 + ln) * 16 + ko;
    const f16* pb = xh2 + ((size_t)(q >> 1) * 4096 + j0 + ln) * 16 + ko;

    f32x4 acc00 = {}, acc01 = {}, acc10 = {}, acc11 = {};

    f16x8 ra0 = *(const f16x8*)(pa);
    f16x8 ra1 = *(const f16x8*)(pa + 256);
    f16x8 rb0 = *(const f16x8*)(pb);
    f16x8 rb1 = *(const f16x8*)(pb + 256);

    for (int kk = 0; kk < 8; kk++) {
        f16x8 sa0 = *(const f16x8*)(pa + 4096);
        f16x8 sa1 = *(const f16x8*)(pa + 4096 + 256);
        f16x8 sb0 = *(const f16x8*)(pb + 131072);
        f16x8 sb1 = *(const f16x8*)(pb + 131072 + 256);
        acc00 = __builtin_amdgcn_mfma_f32_16x16x32_f16(ra0, rb0, acc00, 0, 0, 0);
        acc01 = __builtin_amdgcn_mfma_f32_16x16x32_f16(ra0, rb1, acc01, 0, 0, 0);
        acc10 = __builtin_amdgcn_mfma_f32_16x16x32_f16(ra1, rb0, acc10, 0, 0, 0);
        acc11 = __builtin_amdgcn_mfma_f32_16x16x32_f16(ra1, rb1, acc11, 0, 0, 0);
        pa += 8192; pb += 262144;
        ra0 = *(const f16x8*)(pa);
        ra1 = *(const f16x8*)(pa + 256);
        rb0 = *(const f16x8*)(pb);
        rb1 = *(const f16x8*)(pb + 256);
        acc00 = __builtin_amdgcn_mfma_f32_16x16x32_f16(sa0, sb0, acc00, 0, 0, 0);
        acc01 = __builtin_amdgcn_mfma_f32_16x16x32_f16(sa0, sb1, acc01, 0, 0, 0);
        acc10 = __builtin_amdgcn_mfma_f32_16x16x32_f16(sa1, sb0, acc10, 0, 0, 0);
        acc11 = __builtin_amdgcn_mfma_f32_16x16x32_f16(sa1, sb1, acc11, 0, 0, 0);
    }

    size_t hb = (size_t)h * 524288 + (size_t)(j0 >> 4) * 2048;
    #pragma unroll
    for (int r = 0; r < 4; r++) {
        int f0 = w * 32 + q * 4 + r;
        hbT2[hb + f0 * 16 + ln]                 = (f16)acc00[r];
        hbT2[hb + 2048 + f0 * 16 + ln]          = (f16)acc01[r];
        hbT2[hb + (f0 + 16) * 16 + ln]          = (f16)acc10[r];
        hbT2[hb + 2048 + (f0 + 16) * 16 + ln]   = (f16)acc11[r];
    }

    float pa0 = 0.f, pb0 = 0.f, pa1 = 0.f, pb1 = 0.f;
    #pragma unroll
    for (int r = 0; r < 4; r++) {
        int f0 = w * 32 + q * 4 + r;
        float w0 = swi[f0], jv0 = swj[f0];
        float w1 = swi[f0 + 16], jv1 = swj[f0 + 16];
        pa0 += acc00[r] * w0 + acc10[r] * w1;
        pb0 += acc00[r] * jv0 + acc10[r] * jv1;
        pa1 += acc01[r] * w0 + acc11[r] * w1;
        pb1 += acc01[r] * jv0 + acc11[r] * jv1;
    }
    pa0 += __shfl_xor(pa0, 16); pa0 += __shfl_xor(pa0, 32);
    pb0 += __shfl_xor(pb0, 16); pb0 += __shfl_xor(pb0, 32);
    pa1 += __shfl_xor(pa1, 16); pa1 += __shfl_xor(pa1, 32);
    pb1 += __shfl_xor(pb1, 16); pb1 += __shfl_xor(pb1, 32);
    if (lane < 16) {
        pwa[w][ln] = pa0;      pwb[w][ln] = pb0;
        pwa[w][16 + ln] = pa1; pwb[w][16 + ln] = pb1;
    }
    __syncthreads();
    if (tid < 32) {
        int jj = tid;
        float pav = (pwa[0][jj] + pwa[1][jj]) + (pwa[2][jj] + pwa[3][jj]);
        float pbv = (pwb[0][jj] + pwb[1][jj]) + (pwb[2][jj] + pwb[3][jj]);
        a2[h * 4096 + j0 + jj] = pav * LOG2E;
        float bb = pbv * LOG2E;
        b2[h * 4096 + j0 + jj] = bb;
        float m = bb;
        m = fmaxf(m, __shfl_xor(m, 1, 32));
        m = fmaxf(m, __shfl_xor(m, 2, 32));
        m = fmaxf(m, __shfl_xor(m, 4, 32));
        m = fmaxf(m, __shfl_xor(m, 8, 32));
        m = fmaxf(m, __shfl_xor(m, 16, 32));
        if (jj == 0) {
            unsigned u = __float_as_uint(m);
            unsigned enc = (u & 0x80000000u) ? ~u : (u | 0x80000000u);
            atomicMax(&M2e[h], enc);
        }
    }
}

// ---------------- Kernel 5: packed, j-pair-split exp tables ----------------
// ABp2[i] = {2^(u-m2), 2^(.2u-m2)} ; Bv2[jp] = {2^t(2jp), 2^t(2jp+1)} ; Bw2 = 0.2-powers
__global__ __launch_bounds__(256) void k_prep(const float* __restrict__ a2,
                                              const float* __restrict__ b2,
                                              const unsigned int* __restrict__ M2e,
                                              unsigned int* __restrict__ ABp2,
                                              unsigned int* __restrict__ Bv2,
                                              unsigned int* __restrict__ Bw2) {
    int id = blockIdx.x * 256 + threadIdx.x;   // 16384: one j-pair each
    int h = id >> 11;
    unsigned enc = M2e[h];
    unsigned u = (enc & 0x80000000u) ? (enc & 0x7FFFFFFFu) : ~enc;
    float M2 = __uint_as_float(u);
    int j2 = id * 2;
    union { h16x2 p; unsigned int i; } pk;
    #pragma unroll
    for (int s = 0; s < 2; s++) {
        float av = a2[j2 + s];
        float uu = av + M2;
        float m2 = fmaxf(uu, NSL * uu);
        pk.p = __builtin_amdgcn_cvt_pkrtz(exp2f(uu - m2), exp2f(NSL * uu - m2));
        ABp2[j2 + s] = pk.i;
    }
    float t0 = b2[j2] - M2, t1 = b2[j2 + 1] - M2;
    pk.p = __builtin_amdgcn_cvt_pkrtz(exp2f(t0), exp2f(t1));
    Bv2[id] = pk.i;
    pk.p = __builtin_amdgcn_cvt_pkrtz(exp2f(NSL * t0), exp2f(NSL * t1));
    Bw2[id] = pk.i;
}

// ---------------- Kernel 6 helpers ----------------
// packed PGEN over 8 j (4 pairs): qv/qw int4 of {B,B} / {B',B'} pairs.
// mask applied via sign-expanded 32-bit AND (no per-element cndmask).
#define PGEN2(af, m8, qv, qw)                                                        \
    {                                                                                \
        union { int4 i4; unsigned u[4]; } uv, uw;                                    \
        uv.i4 = (qv); uw.i4 = (qw);                                                  \
        f16x2v dl = {(_Float16)0, (_Float16)0};                                      \
        _Pragma("unroll")                                                            \
        for (int p = 0; p < 4; p++) {                                                \
            union { unsigned u; f16x2v v; } b1, b2x, mm;                             \
            b1.u = uv.u[p]; b2x.u = uw.u[p];                                         \
            f16x2v pr1 = Ap1 * b1.v;                                                 \
            f16x2v pr2 = Ap2 * b2x.v;                                                \
            mm.v = __builtin_elementwise_max(pr1, pr2);                              \
            int mlo = -(int)(((m8) >> (2 * p)) & 1u);                                \
            int mhi = -(int)(((m8) >> (2 * p + 1)) & 1u);                            \
            unsigned comb = ((unsigned)mlo & 0xFFFFu) | ((unsigned)mhi & 0xFFFF0000u);\
            mm.u &= comb;                                                            \
            af.u[p] = mm.u;                                                          \
            dl += mm.v;                                                              \
        }                                                                            \
        dsum += (float)dl.x + (float)dl.y;                                           \
    }

#define PUTACC(dp, off, accv)                                                    \
    {                                                                            \
        union { f32x16 v; f32x4 q[4]; } t; t.v = (accv);                         \
        *(f32x4*)((dp) + (off))      = t.q[0];                                   \
        *(f32x4*)((dp) + (off) + 4)  = t.q[1];                                   \
        *(f32x4*)((dp) + (off) + 8)  = t.q[2];                                   \
        *(f32x4*)((dp) + (off) + 12) = t.q[3];                                   \
    }

#define ADDACC(dp, off, accv)                                                    \
    {                                                                            \
        union { f32x16 v; f32x4 q[4]; } t; t.v = (accv);                         \
        t.q[0] += *(const f32x4*)((dp) + (off));                                 \
        t.q[1] += *(const f32x4*)((dp) + (off) + 4);                             \
        t.q[2] += *(const f32x4*)((dp) + (off) + 8);                             \
        t.q[3] += *(const f32x4*)((dp) + (off) + 12);                            \
        (accv) = t.v;                                                            \
    }

// ---------------- Kernel 6: main — LDS-staged tables, pk_max PGEN, AND-masking ----------------
__global__ __launch_bounds__(256, 4) void k_main(const f16* __restrict__ xh2,
                                                 const f16* __restrict__ hbT2,
                                                 const f16* __restrict__ Wrt2,
                                                 const unsigned int* __restrict__ maskJ,
                                                 const unsigned int* __restrict__ ABp2,
                                                 const unsigned int* __restrict__ Bv2,
                                                 const unsigned int* __restrict__ Bw2,
                                                 const float* __restrict__ bias,
                                                 float* __restrict__ out) {
    __shared__ char smem[35328];          // [0,16512) mask[32][129] | [16512,24704) Bv | [24704,32896) Bw
    __shared__ float dred[128];           // (all dead after loop; xred[2][64*68] aliases [0,34816))

    unsigned int* mlds = (unsigned int*)smem;
    unsigned int* bvlds = (unsigned int*)(smem + 16512);
    unsigned int* bwlds = (unsigned int*)(smem + 24704);

    int bx = blockIdx.x;
    int h = bx & 7, it = bx >> 3;
    int i0 = it * 32;
    int tid = threadIdx.x;
    int w = tid >> 6, lane = tid & 63;
    int l31 = lane & 31, half = lane >> 5;
    int i = i0 + l31;

    // ---- stage Bv/Bw tables (2048 uints each) and mask strip into LDS ----
    {
        const int4* vsrc = (const int4*)(Bv2 + h * 2048);
        const int4* wsrc = (const int4*)(Bw2 + h * 2048);
        int4* vdst = (int4*)bvlds;
        int4* wdst = (int4*)bwlds;
        #pragma unroll
        for (int c = 0; c < 2; c++) {
            vdst[tid + c * 256] = vsrc[tid + c * 256];
            wdst[tid + c * 256] = wsrc[tid + c * 256];
        }
        #pragma unroll
        for (int c = 0; c < 16; c++) {
            int e = tid + c * 256;                 // e = jw*32 + i
            int jw = e >> 5, ii = e & 31;
            mlds[ii * 129 + jw] = maskJ[(size_t)jw * 4096 + i0 + ii];
        }
    }

    union { unsigned u; f16x2v v; } apc;
    apc.u = ABp2[h * 4096 + i];
    f16x2v Ap1 = {apc.v.x, apc.v.x};
    f16x2v Ap2 = {apc.v.y, apc.v.y};

    f32x16 acc0 = {}, acc1 = {}, acc2 = {}, acc3 = {};
    float dsum = 0.f;

    int J0 = w * 1024;
    const f16* bb = hbT2 + (size_t)h * 524288 + ((size_t)(J0 >> 4) * 128 + l31) * 16 + half * 8;
    const unsigned int* bpv = bvlds + (J0 >> 1) + half * 4;   // wave-uniform per half -> broadcast
    const unsigned int* bpw = bwlds + (J0 >> 1) + half * 4;
    const unsigned int* mrow = mlds + l31 * 129 + (J0 >> 5);

    int sh0 = half << 3;
    int sh1 = 16 + (half << 3);

    __syncthreads();

    // prologue: frags + table pairs for tile 0, mask word for pair 0
    f16x8 fa0 = *(const f16x8*)(bb);
    f16x8 fa1 = *(const f16x8*)(bb + 512);
    f16x8 fa2 = *(const f16x8*)(bb + 1024);
    f16x8 fa3 = *(const f16x8*)(bb + 1536);
    int4 qv0 = ((const int4*)(bpv))[0];
    int4 qw0 = ((const int4*)(bpw))[0];
    unsigned mwc = mrow[0];

    for (int tp = 0; tp < 32; tp++) {
        int t0 = tp * 2;
        // prefetch odd tile
        const f16* s1 = bb + (size_t)(t0 + 1) * 2048;
        f16x8 fb0 = *(const f16x8*)(s1);
        f16x8 fb1 = *(const f16x8*)(s1 + 512);
        f16x8 fb2 = *(const f16x8*)(s1 + 1024);
        f16x8 fb3 = *(const f16x8*)(s1 + 1536);
        int4 qv1 = *(const int4*)(bpv + (t0 + 1) * 8);
        int4 qw1 = *(const int4*)(bpw + (t0 + 1) * 8);
        unsigned mwn = mrow[tp + 1];

        // body even t0
        {
            union { f16x8 v; unsigned u[4]; } af;
            PGEN2(af, mwc >> sh0, qv0, qw0);
            acc0 = __builtin_amdgcn_mfma_f32_32x32x16_f16(af.v, fa0, acc0, 0, 0, 0);
            acc1 = __builtin_amdgcn_mfma_f32_32x32x16_f16(af.v, fa1, acc1, 0, 0, 0);
            acc2 = __builtin_amdgcn_mfma_f32_32x32x16_f16(af.v, fa2, acc2, 0, 0, 0);
            acc3 = __builtin_amdgcn_mfma_f32_32x32x16_f16(af.v, fa3, acc3, 0, 0, 0);
        }

        // prefetch next even tile (last-iter overrun stays inside workspace / LDS)
        const f16* s2 = bb + (size_t)(t0 + 2) * 2048;
        fa0 = *(const f16x8*)(s2);
        fa1 = *(const f16x8*)(s2 + 512);
        fa2 = *(const f16x8*)(s2 + 1024);
        fa3 = *(const f16x8*)(s2 + 1536);
        qv0 = *(const int4*)(bpv + (t0 + 2) * 8);
        qw0 = *(const int4*)(bpw + (t0 + 2) * 8);

        // body odd t0+1
        {
            union { f16x8 v; unsigned u[4]; } af;
            PGEN2(af, mwc >> sh1, qv1, qw1);
            acc0 = __builtin_amdgcn_mfma_f32_32x32x16_f16(af.v, fb0, acc0, 0, 0, 0);
            acc1 = __builtin_amdgcn_mfma_f32_32x32x16_f16(af.v, fb1, acc1, 0, 0, 0);
            acc2 = __builtin_amdgcn_mfma_f32_32x32x16_f16(af.v, fb2, acc2, 0, 0, 0);
            acc3 = __builtin_amdgcn_mfma_f32_32x32x16_f16(af.v, fb3, acc3, 0, 0, 0);
        }
        mwc = mwn;
    }

    // ---- denominator: combine j-halves in-wave, then cross-wave via LDS ----
    dsum += __shfl(dsum, lane ^ 32);
    if (lane < 32) dred[w * 32 + l31] = dsum;
    __syncthreads();
    {
        #pragma unroll
        for (int r = 0; r < 16; r++) {
            int row = (r & 3) + 8 * (r >> 2) + 4 * half;
            float s = dred[row] + dred[32 + row] + dred[64 + row] + dred[96 + row];
            float inv = 1.0f / s;
            acc0[r] *= inv; acc1[r] *= inv; acc2[r] *= inv; acc3[r] *= inv;
        }
    }

    // ---- residual: acc += x @ Wr[:, h-slice]; k-quarter per wave ----
    {
        #pragma unroll
        for (int kt = 0; kt < 8; kt++) {
            int ktt = w * 8 + kt;
            f16x8 ax = *(const f16x8*)(xh2 + ((size_t)ktt * 4096 + i) * 16 + half * 8);
            const f16* wb = Wrt2 + ((size_t)ktt * 1024 + h * 128 + l31) * 16 + half * 8;
            acc0 = __builtin_amdgcn_mfma_f32_32x32x16_f16(ax, *(const f16x8*)(wb), acc0, 0, 0, 0);
            acc1 = __builtin_amdgcn_mfma_f32_32x32x16_f16(ax, *(const f16x8*)(wb + 512), acc1, 0, 0, 0);
            acc2 = __builtin_amdgcn_mfma_f32_32x32x16_f16(ax, *(const f16x8*)(wb + 1024), acc2, 0, 0, 0);
            acc3 = __builtin_amdgcn_mfma_f32_32x32x16_f16(ax, *(const f16x8*)(wb + 1536), acc3, 0, 0, 0);
        }
    }

    // ---- cross-wave O reduction (xred aliases staging LDS, dead since loop end) ----
    float* xredb = (float*)smem;
    __syncthreads();   // dred reads done; smem reusable
    if (w >= 2) {
        float* dp = xredb + (w - 2) * 4352 + lane * 68;
        PUTACC(dp, 0, acc0); PUTACC(dp, 16, acc1); PUTACC(dp, 32, acc2); PUTACC(dp, 48, acc3);
    }
    __syncthreads();
    if (w < 2) {
        const float* dp = xredb + w * 4352 + lane * 68;
        ADDACC(dp, 0, acc0); ADDACC(dp, 16, acc1); ADDACC(dp, 32, acc2); ADDACC(dp, 48, acc3);
    }
    __syncthreads();
    if (w == 1) {
        float* dp = xredb + lane * 68;
        PUTACC(dp, 0, acc0); PUTACC(dp, 16, acc1); PUTACC(dp, 32, acc2); PUTACC(dp, 48, acc3);
    }
    __syncthreads();
    if (w == 0) {
        const float* dp = xredb + lane * 68;
        ADDACC(dp, 0, acc0); ADDACC(dp, 16, acc1); ADDACC(dp, 32, acc2); ADDACC(dp, 48, acc3);
        #pragma unroll
        for (int n = 0; n < 4; n++) {
            union { f32x16 v; f32x4 q[4]; } t;
            t.v = (n == 0) ? acc0 : (n == 1) ? acc1 : (n == 2) ? acc2 : acc3;
            int col = h * 128 + n * 32 + l31;
            float bv = bias[col];
            #pragma unroll
            for (int r = 0; r < 16; r++) {
                int row = i0 + (r & 3) + 8 * (r >> 2) + 4 * half;
                out[(size_t)row * 1024 + col] = t.v[r] + bv;
            }
        }
    }
}

extern "C" void kernel_launch(void* const* d_in, const int* in_sizes, int n_in,
                              void* d_out, int out_size, void* d_ws, size_t ws_size,
                              hipStream_t stream) {
    (void)in_sizes; (void)n_in; (void)out_size; (void)ws_size;
    const float* x     = (const float*)d_in[0];
    const int*   graph = (const int*)d_in[1];
    const float* W     = (const float*)d_in[2];
    const float* wi    = (const float*)d_in[3];
    const float* wj    = (const float*)d_in[4];
    const float* Wr    = (const float*)d_in[5];
    const float* bias  = (const float*)d_in[6];
    float* out = (float*)d_out;

    char* ws = (char*)d_ws;
    unsigned int* maskJ = (unsigned int*)ws;              // 2 MB  [128 jw][4096 i]
    f16* hbT2  = (f16*)(ws + (2u << 20));                 // 8 MB  [8][(j>>4)*128+f][j&15]
    f16* Wht2  = (f16*)(ws + (10u << 20));                // 1 MB  swizzled
    f16* Wrt2  = (f16*)(ws + (11u << 20));                // 1 MB  swizzled
    f16* xh2   = (f16*)(ws + (12u << 20));                // 4 MB  [32][4096][16] swizzled
    float* a2    = (float*)(ws + (16u << 20));            // 128 KB
    float* b2    = a2 + 8 * 4096;                         // 128 KB
    unsigned int* ABp2 = (unsigned int*)(b2 + 8 * 4096);  // 128 KB packed f16x2
    unsigned int* Bv2  = ABp2 + 8 * 4096;                 // 64 KB packed j-pairs
    unsigned int* Bw2  = Bv2 + 8 * 2048;                  // 64 KB packed j-pairs
    unsigned int* M2e  = Bw2 + 8 * 2048;                  // 32 B

    hipLaunchKernelGGL(k_pre, dim3(2560), dim3(256), 0, stream,
                       graph, maskJ, M2e, x, xh2, W, Wht2, Wr, Wrt2);
    hipLaunchKernelGGL(k_gemm_h, dim3(1024), dim3(256), 0, stream, xh2, Wht2, hbT2,
                       wi, wj, a2, b2, M2e);
    hipLaunchKernelGGL(k_prep, dim3(64), dim3(256), 0, stream, a2, b2, M2e, ABp2, Bv2, Bw2);
    hipLaunchKernelGGL(k_main, dim3(1024), dim3(256), 0, stream, xh2, hbT2, Wrt2, maskJ,
                       ABp2, Bv2, Bw2, bias, out);
}

// Round 15
// 218.884 us; speedup vs baseline: 1.1434x; 1.0388x over previous
//
#include <hip/hip_runtime.h>
#include <hip/hip_fp16.h>

typedef _Float16 f16;
typedef _Float16 f16x8 __attribute__((ext_vector_type(8)));
typedef _Float16 f16x2v __attribute__((ext_vector_type(2)));
typedef __fp16 h16x2 __attribute__((ext_vector_type(2)));
typedef float f32x4 __attribute__((ext_vector_type(4)));
typedef float f32x16 __attribute__((ext_vector_type(16)));

#define LOG2E 1.4426950408889634f
#define NSL 0.2f

// ---------------- Kernel A: xcvt + swizzled weight transposes + M2e init ----------------
__global__ __launch_bounds__(256) void k_a(const float* __restrict__ x,
                                           f16* __restrict__ xh2,
                                           const float* __restrict__ W,
                                           f16* __restrict__ Wht2,
                                           const float* __restrict__ Wr,
                                           f16* __restrict__ Wrt2,
                                           unsigned int* __restrict__ M2e) {
    __shared__ float tile[32][33];
    int bx = blockIdx.x;
    int tid = threadIdx.x;
    if (bx == 0 && tid < 8) M2e[tid] = 0x007FFFFFu;  // enc(-inf)
    if (bx < 512) {
        int id = bx * 256 + tid;   // 131072
        int row = id & 4095, kt = id >> 12;
        const float4* xs = (const float4*)(x + (size_t)row * 512 + kt * 16);
        float4 u0 = xs[0], u1 = xs[1], u2 = xs[2], u3 = xs[3];
        union { int4 a[2]; h16x2 p[8]; } px;
        px.p[0] = __builtin_amdgcn_cvt_pkrtz(u0.x, u0.y);
        px.p[1] = __builtin_amdgcn_cvt_pkrtz(u0.z, u0.w);
        px.p[2] = __builtin_amdgcn_cvt_pkrtz(u1.x, u1.y);
        px.p[3] = __builtin_amdgcn_cvt_pkrtz(u1.z, u1.w);
        px.p[4] = __builtin_amdgcn_cvt_pkrtz(u2.x, u2.y);
        px.p[5] = __builtin_amdgcn_cvt_pkrtz(u2.z, u2.w);
        px.p[6] = __builtin_amdgcn_cvt_pkrtz(u3.x, u3.y);
        px.p[7] = __builtin_amdgcn_cvt_pkrtz(u3.z, u3.w);
        int4* d = (int4*)(xh2 + ((size_t)kt * 4096 + row) * 16);
        d[0] = px.a[0]; d[1] = px.a[1];
    } else {
        const float* in; f16* out; int C, S, bxx, byy;
        if (bx < 1024) { int id = bx - 512;  in = W;  out = Wht2; C = 128;  S = 128;  bxx = id & 3;  byy = id >> 2; }
        else           { int id = bx - 1024; in = Wr; out = Wrt2; C = 1024; S = 1024; bxx = id & 31; byy = id >> 5; }
        int tx = tid & 31, ty = tid >> 5;
        int c0 = bxx * 32, r0 = byy * 32;
        for (int rr = ty; rr < 32; rr += 8)
            tile[rr][tx] = in[(r0 + rr) * C + c0 + tx];
        __syncthreads();
        for (int rr = ty; rr < 32; rr += 8) {
            int m = r0 + tx, f = c0 + rr;
            out[(size_t)((m >> 4) * S + f) * 16 + (m & 15)] = (f16)tile[tx][rr];
        }
    }
}

// ---------------- Kernel B (fused): gemm_h (blocks 0..1023) + graph bitmask (1024..2047) ----------------
// Mask build is HBM-bound; gemm is compute/latency-bound -> concurrent execution hides mask time.
__global__ __launch_bounds__(256, 4) void k_b(const f16* __restrict__ xh2,
                                              const f16* __restrict__ Wht2,
                                              f16* __restrict__ hbT2,
                                              const float* __restrict__ wi,
                                              const float* __restrict__ wj,
                                              float* __restrict__ a2,
                                              float* __restrict__ b2,
                                              unsigned int* __restrict__ M2e,
                                              const int* __restrict__ graph,
                                              unsigned int* __restrict__ maskJ) {
    __shared__ float swi[128], swj[128];
    __shared__ float pwa[4][32], pwb[4][32];
    __shared__ unsigned long long bal[4][64];
    int bx = blockIdx.x;
    int tid = threadIdx.x;
    int w = tid >> 6, lane = tid & 63;

    if (bx >= 1024) {
        // ---- mask part ----
        int gw = (bx - 1024) * 4 + w;
        int ti = gw & 63, tj = gw >> 6;
        int i0 = ti * 64, j0 = tj * 64;
        #pragma unroll 8
        for (int k = 0; k < 64; k++) {
            int g = graph[(j0 + k) * 4096 + i0 + lane];
            unsigned long long b = __ballot(g > 0);
            if (lane == 0) bal[w][k] = b;
        }
        __syncthreads();
        unsigned long long word = 0;
        #pragma unroll 8
        for (int k = 0; k < 64; k++) {
            word |= ((bal[w][k] >> lane) & 1ull) << k;
        }
        int jw = j0 >> 5;
        maskJ[(size_t)jw * 4096 + i0 + lane]       = (unsigned int)word;
        maskJ[(size_t)(jw + 1) * 4096 + i0 + lane] = (unsigned int)(word >> 32);
        return;
    }

    // ---- gemm part ----
    int h = bx & 7, jb = bx >> 3;        // 128 j-tiles of 32
    int j0 = jb * 32;
    int ln = lane & 15, q = lane >> 4;
    if (tid < 128) { swi[tid] = wi[h * 128 + tid]; swj[tid] = wj[h * 128 + tid]; }
    __syncthreads();

    int ko = (q & 1) * 8;
    const f16* pa = Wht2 + ((size_t)(h * 512) * 8 + (size_t)(q >> 1) * 128 + w * 32 + ln) * 16 + ko;
    const f16* pb = xh2 + ((size_t)(q >> 1) * 4096 + j0 + ln) * 16 + ko;

    f32x4 acc00 = {}, acc01 = {}, acc10 = {}, acc11 = {};

    f16x8 ra0 = *(const f16x8*)(pa);
    f16x8 ra1 = *(const f16x8*)(pa + 256);
    f16x8 rb0 = *(const f16x8*)(pb);
    f16x8 rb1 = *(const f16x8*)(pb + 256);

    for (int kk = 0; kk < 8; kk++) {
        f16x8 sa0 = *(const f16x8*)(pa + 4096);
        f16x8 sa1 = *(const f16x8*)(pa + 4096 + 256);
        f16x8 sb0 = *(const f16x8*)(pb + 131072);
        f16x8 sb1 = *(const f16x8*)(pb + 131072 + 256);
        acc00 = __builtin_amdgcn_mfma_f32_16x16x32_f16(ra0, rb0, acc00, 0, 0, 0);
        acc01 = __builtin_amdgcn_mfma_f32_16x16x32_f16(ra0, rb1, acc01, 0, 0, 0);
        acc10 = __builtin_amdgcn_mfma_f32_16x16x32_f16(ra1, rb0, acc10, 0, 0, 0);
        acc11 = __builtin_amdgcn_mfma_f32_16x16x32_f16(ra1, rb1, acc11, 0, 0, 0);
        pa += 8192; pb += 262144;
        ra0 = *(const f16x8*)(pa);
        ra1 = *(const f16x8*)(pa + 256);
        rb0 = *(const f16x8*)(pb);
        rb1 = *(const f16x8*)(pb + 256);
        acc00 = __builtin_amdgcn_mfma_f32_16x16x32_f16(sa0, sb0, acc00, 0, 0, 0);
        acc01 = __builtin_amdgcn_mfma_f32_16x16x32_f16(sa0, sb1, acc01, 0, 0, 0);
        acc10 = __builtin_amdgcn_mfma_f32_16x16x32_f16(sa1, sb0, acc10, 0, 0, 0);
        acc11 = __builtin_amdgcn_mfma_f32_16x16x32_f16(sa1, sb1, acc11, 0, 0, 0);
    }

    size_t hb = (size_t)h * 524288 + (size_t)(j0 >> 4) * 2048;
    #pragma unroll
    for (int r = 0; r < 4; r++) {
        int f0 = w * 32 + q * 4 + r;
        hbT2[hb + f0 * 16 + ln]                 = (f16)acc00[r];
        hbT2[hb + 2048 + f0 * 16 + ln]          = (f16)acc01[r];
        hbT2[hb + (f0 + 16) * 16 + ln]          = (f16)acc10[r];
        hbT2[hb + 2048 + (f0 + 16) * 16 + ln]   = (f16)acc11[r];
    }

    float pa0 = 0.f, pb0 = 0.f, pa1 = 0.f, pb1 = 0.f;
    #pragma unroll
    for (int r = 0; r < 4; r++) {
        int f0 = w * 32 + q * 4 + r;
        float w0 = swi[f0], jv0 = swj[f0];
        float w1 = swi[f0 + 16], jv1 = swj[f0 + 16];
        pa0 += acc00[r] * w0 + acc10[r] * w1;
        pb0 += acc00[r] * jv0 + acc10[r] * jv1;
        pa1 += acc01[r] * w0 + acc11[r] * w1;
        pb1 += acc01[r] * jv0 + acc11[r] * jv1;
    }
    pa0 += __shfl_xor(pa0, 16); pa0 += __shfl_xor(pa0, 32);
    pb0 += __shfl_xor(pb0, 16); pb0 += __shfl_xor(pb0, 32);
    pa1 += __shfl_xor(pa1, 16); pa1 += __shfl_xor(pa1, 32);
    pb1 += __shfl_xor(pb1, 16); pb1 += __shfl_xor(pb1, 32);
    if (lane < 16) {
        pwa[w][ln] = pa0;      pwb[w][ln] = pb0;
        pwa[w][16 + ln] = pa1; pwb[w][16 + ln] = pb1;
    }
    __syncthreads();
    if (tid < 32) {
        int jj = tid;
        float pav = (pwa[0][jj] + pwa[1][jj]) + (pwa[2][jj] + pwa[3][jj]);
        float pbv = (pwb[0][jj] + pwb[1][jj]) + (pwb[2][jj] + pwb[3][jj]);
        a2[h * 4096 + j0 + jj] = pav * LOG2E;
        float bb = pbv * LOG2E;
        b2[h * 4096 + j0 + jj] = bb;
        float m = bb;
        m = fmaxf(m, __shfl_xor(m, 1, 32));
        m = fmaxf(m, __shfl_xor(m, 2, 32));
        m = fmaxf(m, __shfl_xor(m, 4, 32));
        m = fmaxf(m, __shfl_xor(m, 8, 32));
        m = fmaxf(m, __shfl_xor(m, 16, 32));
        if (jj == 0) {
            unsigned u = __float_as_uint(m);
            unsigned enc = (u & 0x80000000u) ? ~u : (u | 0x80000000u);
            atomicMax(&M2e[h], enc);
        }
    }
}

// ---------------- Kernel 6 helpers ----------------
#define PGEN2(af, m8, qv, qw)                                                        \
    {                                                                                \
        union { int4 i4; unsigned u[4]; } uv, uw;                                    \
        uv.i4 = (qv); uw.i4 = (qw);                                                  \
        f16x2v dl = {(_Float16)0, (_Float16)0};                                      \
        _Pragma("unroll")                                                            \
        for (int p = 0; p < 4; p++) {                                                \
            union { unsigned u; f16x2v v; } b1, b2x, mm;                             \
            b1.u = uv.u[p]; b2x.u = uw.u[p];                                         \
            f16x2v pr1 = Ap1 * b1.v;                                                 \
            f16x2v pr2 = Ap2 * b2x.v;                                                \
            mm.v = __builtin_elementwise_max(pr1, pr2);                              \
            int mlo = -(int)(((m8) >> (2 * p)) & 1u);                                \
            int mhi = -(int)(((m8) >> (2 * p + 1)) & 1u);                            \
            unsigned comb = ((unsigned)mlo & 0xFFFFu) | ((unsigned)mhi & 0xFFFF0000u);\
            mm.u &= comb;                                                            \
            af.u[p] = mm.u;                                                          \
            dl += mm.v;                                                              \
        }                                                                            \
        dsum += (float)dl.x + (float)dl.y;                                           \
    }

#define PUTACC(dp, off, accv)                                                    \
    {                                                                            \
        union { f32x16 v; f32x4 q[4]; } t; t.v = (accv);                         \
        *(f32x4*)((dp) + (off))      = t.q[0];                                   \
        *(f32x4*)((dp) + (off) + 4)  = t.q[1];                                   \
        *(f32x4*)((dp) + (off) + 8)  = t.q[2];                                   \
        *(f32x4*)((dp) + (off) + 12) = t.q[3];                                   \
    }

#define ADDACC(dp, off, accv)                                                    \
    {                                                                            \
        union { f32x16 v; f32x4 q[4]; } t; t.v = (accv);                         \
        t.q[0] += *(const f32x4*)((dp) + (off));                                 \
        t.q[1] += *(const f32x4*)((dp) + (off) + 4);                             \
        t.q[2] += *(const f32x4*)((dp) + (off) + 8);                             \
        t.q[3] += *(const f32x4*)((dp) + (off) + 12);                            \
        (accv) = t.v;                                                            \
    }

// ---------------- Kernel 6: main — in-kernel exp-table build (k_prep folded), LDS-staged
// tables/mask, pk_max PGEN, AND-masking, frag reg dbuf, 4 waves/SIMD ----------------
__global__ __launch_bounds__(256, 4) void k_main(const f16* __restrict__ xh2,
                                                 const f16* __restrict__ hbT2,
                                                 const f16* __restrict__ Wrt2,
                                                 const unsigned int* __restrict__ maskJ,
                                                 const float* __restrict__ a2,
                                                 const float* __restrict__ b2,
                                                 const unsigned int* __restrict__ M2e,
                                                 const float* __restrict__ bias,
                                                 float* __restrict__ out) {
    __shared__ char smem[35328];          // [0,16512) mask[32][129] | [16512,24704) Bv | [24704,32896) Bw
    __shared__ float dred[128];           // (all dead after loop; xred aliases [0,34816))

    unsigned int* mlds = (unsigned int*)smem;
    unsigned int* bvlds = (unsigned int*)(smem + 16512);
    unsigned int* bwlds = (unsigned int*)(smem + 24704);

    int bx = blockIdx.x;
    int h = bx & 7, it = bx >> 3;
    int i0 = it * 32;
    int tid = threadIdx.x;
    int w = tid >> 6, lane = tid & 63;
    int l31 = lane & 31, half = lane >> 5;
    int i = i0 + l31;

    unsigned enc = M2e[h];
    unsigned um = (enc & 0x80000000u) ? (enc & 0x7FFFFFFFu) : ~enc;
    float M2 = __uint_as_float(um);

    // ---- build Bv/Bw tables in LDS from b2 (k_prep folded in) + stage mask strip ----
    {
        const float2* bsrc = (const float2*)(b2 + h * 4096);
        #pragma unroll
        for (int c = 0; c < 8; c++) {
            int p = tid + c * 256;                 // 2048 j-pairs
            float2 tb = bsrc[p];
            float t0 = tb.x - M2, t1 = tb.y - M2;
            union { h16x2 pp; unsigned ii; } k1, k2;
            k1.pp = __builtin_amdgcn_cvt_pkrtz(exp2f(t0), exp2f(t1));
            k2.pp = __builtin_amdgcn_cvt_pkrtz(exp2f(NSL * t0), exp2f(NSL * t1));
            bvlds[p] = k1.ii;
            bwlds[p] = k2.ii;
        }
        #pragma unroll
        for (int c = 0; c < 16; c++) {
            int e = tid + c * 256;                 // e = jw*32 + i
            int jw = e >> 5, ii = e & 31;
            mlds[ii * 129 + jw] = maskJ[(size_t)jw * 4096 + i0 + ii];
        }
    }

    // ---- per-row A factors (computed, not table-read) ----
    float av = a2[h * 4096 + i];
    float uu = av + M2;
    float m2v = fmaxf(uu, NSL * uu);
    union { h16x2 pp; f16x2v v; } apk;
    apk.pp = __builtin_amdgcn_cvt_pkrtz(exp2f(uu - m2v), exp2f(NSL * uu - m2v));
    f16x2v Ap1 = {apk.v.x, apk.v.x};
    f16x2v Ap2 = {apk.v.y, apk.v.y};

    f32x16 acc0 = {}, acc1 = {}, acc2 = {}, acc3 = {};
    float dsum = 0.f;

    int J0 = w * 1024;
    const f16* bb = hbT2 + (size_t)h * 524288 + ((size_t)(J0 >> 4) * 128 + l31) * 16 + half * 8;
    const unsigned int* bpv = bvlds + (J0 >> 1) + half * 4;
    const unsigned int* bpw = bwlds + (J0 >> 1) + half * 4;
    const unsigned int* mrow = mlds + l31 * 129 + (J0 >> 5);

    int sh0 = half << 3;
    int sh1 = 16 + (half << 3);

    __syncthreads();

    // prologue
    f16x8 fa0 = *(const f16x8*)(bb);
    f16x8 fa1 = *(const f16x8*)(bb + 512);
    f16x8 fa2 = *(const f16x8*)(bb + 1024);
    f16x8 fa3 = *(const f16x8*)(bb + 1536);
    int4 qv0 = ((const int4*)(bpv))[0];
    int4 qw0 = ((const int4*)(bpw))[0];
    unsigned mwc = mrow[0];

    for (int tp = 0; tp < 32; tp++) {
        int t0 = tp * 2;
        const f16* s1 = bb + (size_t)(t0 + 1) * 2048;
        f16x8 fb0 = *(const f16x8*)(s1);
        f16x8 fb1 = *(const f16x8*)(s1 + 512);
        f16x8 fb2 = *(const f16x8*)(s1 + 1024);
        f16x8 fb3 = *(const f16x8*)(s1 + 1536);
        int4 qv1 = *(const int4*)(bpv + (t0 + 1) * 8);
        int4 qw1 = *(const int4*)(bpw + (t0 + 1) * 8);
        unsigned mwn = mrow[tp + 1];

        {
            union { f16x8 v; unsigned u[4]; } af;
            PGEN2(af, mwc >> sh0, qv0, qw0);
            acc0 = __builtin_amdgcn_mfma_f32_32x32x16_f16(af.v, fa0, acc0, 0, 0, 0);
            acc1 = __builtin_amdgcn_mfma_f32_32x32x16_f16(af.v, fa1, acc1, 0, 0, 0);
            acc2 = __builtin_amdgcn_mfma_f32_32x32x16_f16(af.v, fa2, acc2, 0, 0, 0);
            acc3 = __builtin_amdgcn_mfma_f32_32x32x16_f16(af.v, fa3, acc3, 0, 0, 0);
        }

        const f16* s2 = bb + (size_t)(t0 + 2) * 2048;
        fa0 = *(const f16x8*)(s2);
        fa1 = *(const f16x8*)(s2 + 512);
        fa2 = *(const f16x8*)(s2 + 1024);
        fa3 = *(const f16x8*)(s2 + 1536);
        qv0 = *(const int4*)(bpv + (t0 + 2) * 8);
        qw0 = *(const int4*)(bpw + (t0 + 2) * 8);

        {
            union { f16x8 v; unsigned u[4]; } af;
            PGEN2(af, mwc >> sh1, qv1, qw1);
            acc0 = __builtin_amdgcn_mfma_f32_32x32x16_f16(af.v, fb0, acc0, 0, 0, 0);
            acc1 = __builtin_amdgcn_mfma_f32_32x32x16_f16(af.v, fb1, acc1, 0, 0, 0);
            acc2 = __builtin_amdgcn_mfma_f32_32x32x16_f16(af.v, fb2, acc2, 0, 0, 0);
            acc3 = __builtin_amdgcn_mfma_f32_32x32x16_f16(af.v, fb3, acc3, 0, 0, 0);
        }
        mwc = mwn;
    }

    // ---- denominator ----
    dsum += __shfl(dsum, lane ^ 32);
    if (lane < 32) dred[w * 32 + l31] = dsum;
    __syncthreads();
    {
        #pragma unroll
        for (int r = 0; r < 16; r++) {
            int row = (r & 3) + 8 * (r >> 2) + 4 * half;
            float s = dred[row] + dred[32 + row] + dred[64 + row] + dred[96 + row];
            float inv = 1.0f / s;
            acc0[r] *= inv; acc1[r] *= inv; acc2[r] *= inv; acc3[r] *= inv;
        }
    }

    // ---- residual ----
    {
        #pragma unroll
        for (int kt = 0; kt < 8; kt++) {
            int ktt = w * 8 + kt;
            f16x8 ax = *(const f16x8*)(xh2 + ((size_t)ktt * 4096 + i) * 16 + half * 8);
            const f16* wb = Wrt2 + ((size_t)ktt * 1024 + h * 128 + l31) * 16 + half * 8;
            acc0 = __builtin_amdgcn_mfma_f32_32x32x16_f16(ax, *(const f16x8*)(wb), acc0, 0, 0, 0);
            acc1 = __builtin_amdgcn_mfma_f32_32x32x16_f16(ax, *(const f16x8*)(wb + 512), acc1, 0, 0, 0);
            acc2 = __builtin_amdgcn_mfma_f32_32x32x16_f16(ax, *(const f16x8*)(wb + 1024), acc2, 0, 0, 0);
            acc3 = __builtin_amdgcn_mfma_f32_32x32x16_f16(ax, *(const f16x8*)(wb + 1536), acc3, 0, 0, 0);
        }
    }

    // ---- cross-wave O reduction ----
    float* xredb = (float*)smem;
    __syncthreads();
    if (w >= 2) {
        float* dp = xredb + (w - 2) * 4352 + lane * 68;
        PUTACC(dp, 0, acc0); PUTACC(dp, 16, acc1); PUTACC(dp, 32, acc2); PUTACC(dp, 48, acc3);
    }
    __syncthreads();
    if (w < 2) {
        const float* dp = xredb + w * 4352 + lane * 68;
        ADDACC(dp, 0, acc0); ADDACC(dp, 16, acc1); ADDACC(dp, 32, acc2); ADDACC(dp, 48, acc3);
    }
    __syncthreads();
    if (w == 1) {
        float* dp = xredb + lane * 68;
        PUTACC(dp, 0, acc0); PUTACC(dp, 16, acc1); PUTACC(dp, 32, acc2); PUTACC(dp, 48, acc3);
    }
    __syncthreads();
    if (w == 0) {
        const float* dp = xredb + lane * 68;
        ADDACC(dp, 0, acc0); ADDACC(dp, 16, acc1); ADDACC(dp, 32, acc2); ADDACC(dp, 48, acc3);
        #pragma unroll
        for (int n = 0; n < 4; n++) {
            union { f32x16 v; f32x4 q[4]; } t;
            t.v = (n == 0) ? acc0 : (n == 1) ? acc1 : (n == 2) ? acc2 : acc3;
            int col = h * 128 + n * 32 + l31;
            float bv = bias[col];
            #pragma unroll
            for (int r = 0; r < 16; r++) {
                int row = i0 + (r & 3) + 8 * (r >> 2) + 4 * half;
                out[(size_t)row * 1024 + col] = t.v[r] + bv;
            }
        }
    }
}

extern "C" void kernel_launch(void* const* d_in, const int* in_sizes, int n_in,
                              void* d_out, int out_size, void* d_ws, size_t ws_size,
                              hipStream_t stream) {
    (void)in_sizes; (void)n_in; (void)out_size; (void)ws_size;
    const float* x     = (const float*)d_in[0];
    const int*   graph = (const int*)d_in[1];
    const float* W     = (const float*)d_in[2];
    const float* wi    = (const float*)d_in[3];
    const float* wj    = (const float*)d_in[4];
    const float* Wr    = (const float*)d_in[5];
    const float* bias  = (const float*)d_in[6];
    float* out = (float*)d_out;

    char* ws = (char*)d_ws;
    unsigned int* maskJ = (unsigned int*)ws;              // 2 MB  [128 jw][4096 i]
    f16* hbT2  = (f16*)(ws + (2u << 20));                 // 8 MB  [8][(j>>4)*128+f][j&15]
    f16* Wht2  = (f16*)(ws + (10u << 20));                // 1 MB  swizzled
    f16* Wrt2  = (f16*)(ws + (11u << 20));                // 1 MB  swizzled
    f16* xh2   = (f16*)(ws + (12u << 20));                // 4 MB  [32][4096][16] swizzled
    float* a2    = (float*)(ws + (16u << 20));            // 128 KB
    float* b2    = a2 + 8 * 4096;                         // 128 KB
    unsigned int* M2e = (unsigned int*)(b2 + 8 * 4096);   // 32 B

    hipLaunchKernelGGL(k_a, dim3(1536), dim3(256), 0, stream, x, xh2, W, Wht2, Wr, Wrt2, M2e);
    hipLaunchKernelGGL(k_b, dim3(2048), dim3(256), 0, stream, xh2, Wht2, hbT2,
                       wi, wj, a2, b2, M2e, graph, maskJ);
    hipLaunchKernelGGL(k_main, dim3(1024), dim3(256), 0, stream, xh2, hbT2, Wrt2, maskJ,
                       a2, b2, M2e, bias, out);
}